// Round 15
// baseline (204.898 us; speedup 1.0000x reference)
//
#include <hip/hip_runtime.h>
#include <hip/hip_bf16.h>
#include <math.h>

#define B_ 64
#define L_ 512
#define D_ 768
#define J_ 31
#define S_ 32
#define H_ 100
#define G3 300
#define NC_ 10
#define EMB_ 50

__device__ __forceinline__ float sigmoidf_(float x) { return 1.0f / (1.0f + __expf(-x)); }
__device__ __forceinline__ float tanhf_(float x) {
    float e = __expf(2.0f * x);
    return 1.0f - 2.0f / (e + 1.0f);
}
__device__ __forceinline__ float dot4f_(float4 a, float4 b) {
    return a.x * b.x + a.y * b.y + a.z * b.z + a.w * b.w;
}

typedef _Float16 half2_t __attribute__((ext_vector_type(2)));
__device__ __forceinline__ half2_t u_as_h2(unsigned u) { return __builtin_bit_cast(half2_t, u); }
__device__ __forceinline__ unsigned packh2(float a, float b) {
    half2_t p; p.x = (_Float16)a; p.y = (_Float16)b;
    return __builtin_bit_cast(unsigned, p);
}

// ---------------------------------------------------------------------------
// K1: per-clause pooling — single-pass online softmax, one barrier.
// ---------------------------------------------------------------------------
__global__ __launch_bounds__(256) void pool_kernel(
    const float* __restrict__ hs, const int* __restrict__ cb,
    const float* __restrict__ fc5w, const float* __restrict__ fc5b,
    float* __restrict__ doc)
{
    __shared__ __align__(16) float acc_s[4][D_];
    __shared__ float m_s[4], l_s[4];

    int s = blockIdx.x, b = blockIdx.y;
    int start = (s == 0) ? 0 : cb[b * J_ + s - 1];
    int end   = (s == J_) ? L_ : cb[b * J_ + s];
    int nt = end - start;
    int tid = threadIdx.x;
    int lane = tid & 63, wv = tid >> 6;

    if (nt <= 0) {
        for (int d = tid; d < D_; d += 256) doc[((size_t)s * B_ + b) * D_ + d] = 0.f;
        return;
    }

    float4 fwv[3];
#pragma unroll
    for (int i = 0; i < 3; ++i)
        fwv[i] = *(const float4*)(fc5w + 4 * lane + 256 * i);
    float bias = fc5b[0];

    const float* base = hs + ((size_t)b * L_ + start) * D_;
    float m = -INFINITY, l = 0.f;
    float4 acc[3];
#pragma unroll
    for (int i = 0; i < 3; ++i) acc[i] = make_float4(0.f, 0.f, 0.f, 0.f);

    for (int t = wv; t < nt; t += 4) {
        const float* row = base + (size_t)t * D_;
        float4 x0 = *(const float4*)(row + 4 * lane);
        float4 x1 = *(const float4*)(row + 4 * lane + 256);
        float4 x2 = *(const float4*)(row + 4 * lane + 512);
        float p = dot4f_(x0, fwv[0]) + dot4f_(x1, fwv[1]) + dot4f_(x2, fwv[2]);
#pragma unroll
        for (int off = 32; off; off >>= 1) p += __shfl_xor(p, off);
        p += bias;
        if (p > m) {
            float sc = __expf(m - p);
            l *= sc;
#pragma unroll
            for (int i = 0; i < 3; ++i) {
                acc[i].x *= sc; acc[i].y *= sc; acc[i].z *= sc; acc[i].w *= sc;
            }
            m = p;
        }
        float e = __expf(p - m);
        l += e;
        acc[0].x += e * x0.x; acc[0].y += e * x0.y; acc[0].z += e * x0.z; acc[0].w += e * x0.w;
        acc[1].x += e * x1.x; acc[1].y += e * x1.y; acc[1].z += e * x1.z; acc[1].w += e * x1.w;
        acc[2].x += e * x2.x; acc[2].y += e * x2.y; acc[2].z += e * x2.z; acc[2].w += e * x2.w;
    }
#pragma unroll
    for (int i = 0; i < 3; ++i)
        *(float4*)&acc_s[wv][4 * lane + 256 * i] = acc[i];
    if (lane == 0) { m_s[wv] = m; l_s[wv] = l; }
    __syncthreads();

    float M = fmaxf(fmaxf(m_s[0], m_s[1]), fmaxf(m_s[2], m_s[3]));
    float f0 = (l_s[0] > 0.f) ? __expf(m_s[0] - M) : 0.f;
    float f1 = (l_s[1] > 0.f) ? __expf(m_s[1] - M) : 0.f;
    float f2 = (l_s[2] > 0.f) ? __expf(m_s[2] - M) : 0.f;
    float f3 = (l_s[3] > 0.f) ? __expf(m_s[3] - M) : 0.f;
    float inv = 1.f / (l_s[0] * f0 + l_s[1] * f1 + l_s[2] * f2 + l_s[3] * f3);
    float* o = doc + ((size_t)s * B_ + b) * D_;
#pragma unroll
    for (int i = 0; i < 3; ++i) {
        int d = tid + 256 * i;
        float num = acc_s[0][d] * f0 + acc_s[1][d] * f1
                  + acc_s[2][d] * f2 + acc_s[3][d] * f3;
        o[d] = num * inv;
    }
}

// ---------------------------------------------------------------------------
// K2: gi = doc @ [Wf;Wb].T + bias via f16 dot2 (pack during staging).
// ---------------------------------------------------------------------------
__global__ __launch_bounds__(256) void gemm_enc(
    const float* __restrict__ A,
    const float* __restrict__ Wf, const float* __restrict__ Wb,
    const float* __restrict__ bf_, const float* __restrict__ bb_,
    float* __restrict__ C)
{
    __shared__ __align__(16) unsigned As[16][68];
    __shared__ __align__(16) unsigned Ws[16][68];
    int n0 = blockIdx.x * 64, m0 = blockIdx.y * 64;
    int tid = threadIdx.x;
    int tx = tid & 15, ty = tid >> 4;
    int lr = tid >> 2, lk4 = tid & 3;
    float acc[4][4] = {};

    for (int kk = 0; kk < 384; kk += 16) {
        {
            const float* ap = A + ((size_t)(m0 + lr)) * D_ + (kk + lk4 * 4) * 2;
            float4 x = *(const float4*)ap;
            float4 y = *(const float4*)(ap + 4);
            As[lk4 * 4 + 0][lr] = packh2(x.x, x.y);
            As[lk4 * 4 + 1][lr] = packh2(x.z, x.w);
            As[lk4 * 4 + 2][lr] = packh2(y.x, y.y);
            As[lk4 * 4 + 3][lr] = packh2(y.z, y.w);
            int n = n0 + lr;
            float4 u = make_float4(0.f, 0.f, 0.f, 0.f);
            float4 v = make_float4(0.f, 0.f, 0.f, 0.f);
            if (n < G3) {
                const float* wp = Wf + (size_t)n * D_ + (kk + lk4 * 4) * 2;
                u = *(const float4*)wp; v = *(const float4*)(wp + 4);
            } else if (n < 600) {
                const float* wp = Wb + (size_t)(n - G3) * D_ + (kk + lk4 * 4) * 2;
                u = *(const float4*)wp; v = *(const float4*)(wp + 4);
            }
            Ws[lk4 * 4 + 0][lr] = packh2(u.x, u.y);
            Ws[lk4 * 4 + 1][lr] = packh2(u.z, u.w);
            Ws[lk4 * 4 + 2][lr] = packh2(v.x, v.y);
            Ws[lk4 * 4 + 3][lr] = packh2(v.z, v.w);
        }
        __syncthreads();
#pragma unroll
        for (int ku = 0; ku < 16; ++ku) {
            uint4 av = *(const uint4*)&As[ku][ty * 4];
            uint4 wv = *(const uint4*)&Ws[ku][tx * 4];
            unsigned aa[4] = {av.x, av.y, av.z, av.w};
            unsigned ww[4] = {wv.x, wv.y, wv.z, wv.w};
#pragma unroll
            for (int i = 0; i < 4; ++i)
#pragma unroll
                for (int jj = 0; jj < 4; ++jj)
                    acc[i][jj] = __builtin_amdgcn_fdot2(u_as_h2(aa[i]), u_as_h2(ww[jj]),
                                                        acc[i][jj], false);
        }
        __syncthreads();
    }
#pragma unroll
    for (int jj = 0; jj < 4; ++jj) {
        int n = n0 + tx * 4 + jj;
        if (n >= 600) continue;
        float bias = (n < G3) ? bf_[n] : bb_[n - G3];
#pragma unroll
        for (int i = 0; i < 4; ++i) {
            int m = m0 + ty * 4 + i;
            C[(size_t)m * 600 + n] = acc[i][jj] + bias;
        }
    }
}

// ---------------------------------------------------------------------------
// K2b: gil = out1 @ W2.T + b2.  M=2048, N=300, K=200, f32 64x64 tiles.
// ---------------------------------------------------------------------------
__global__ __launch_bounds__(256) void gemm_gil(
    const float* __restrict__ A, const float* __restrict__ W,
    const float* __restrict__ bias, float* __restrict__ C)
{
    __shared__ __align__(16) float As[16][68];
    __shared__ __align__(16) float Ws[16][68];
    int n0 = blockIdx.x * 64, m0 = blockIdx.y * 64;
    int tid = threadIdx.x;
    int tx = tid & 15, ty = tid >> 4;
    int lr = tid >> 2, lk4 = tid & 3;
    float acc[4][4] = {};

    for (int kk = 0; kk < 208; kk += 16) {
        int k = kk + lk4 * 4;
        float4 av = make_float4(0.f, 0.f, 0.f, 0.f);
        if (k < 200) av = *(const float4*)(A + (size_t)(m0 + lr) * 200 + k);
        As[lk4 * 4 + 0][lr] = av.x; As[lk4 * 4 + 1][lr] = av.y;
        As[lk4 * 4 + 2][lr] = av.z; As[lk4 * 4 + 3][lr] = av.w;
        int n = n0 + lr;
        float4 wv = make_float4(0.f, 0.f, 0.f, 0.f);
        if (n < G3 && k < 200) wv = *(const float4*)(W + (size_t)n * 200 + k);
        Ws[lk4 * 4 + 0][lr] = wv.x; Ws[lk4 * 4 + 1][lr] = wv.y;
        Ws[lk4 * 4 + 2][lr] = wv.z; Ws[lk4 * 4 + 3][lr] = wv.w;
        __syncthreads();
#pragma unroll
        for (int ki = 0; ki < 16; ++ki) {
            float4 a4 = *(const float4*)&As[ki][ty * 4];
            float4 w4 = *(const float4*)&Ws[ki][tx * 4];
            float ai[4] = {a4.x, a4.y, a4.z, a4.w};
            float wj[4] = {w4.x, w4.y, w4.z, w4.w};
#pragma unroll
            for (int i = 0; i < 4; ++i)
#pragma unroll
                for (int jj = 0; jj < 4; ++jj) acc[i][jj] += ai[i] * wj[jj];
        }
        __syncthreads();
    }
#pragma unroll
    for (int jj = 0; jj < 4; ++jj) {
        int n = n0 + tx * 4 + jj;
        if (n >= G3) continue;
#pragma unroll
        for (int i = 0; i < 4; ++i) {
            int m = m0 + ty * 4 + i;
            C[(size_t)m * G3 + n] = acc[i][jj] + bias[n];
        }
    }
}

// ---------------------------------------------------------------------------
// Kpack: per-thread-contiguous packed-f16 Whh for the scans.
// ---------------------------------------------------------------------------
__global__ __launch_bounds__(400) void pack_whh(
    const float* __restrict__ wf, const float* __restrict__ wb,
    const float* __restrict__ wd, unsigned* __restrict__ wpack)
{
    int m = blockIdx.x;
    const float* whh = (m == 0) ? wf : (m == 1) ? wb : wd;
    int tid = threadIdx.x;
    int j = tid >> 2, q = tid & 3;
    unsigned* o = wpack + (size_t)m * 16000 + (size_t)tid * 40;
#pragma unroll
    for (int d = 0; d < 13; ++d) {
        int k = 2 * (13 * q + d);
        float r0 = (k < H_) ? whh[j * H_ + k] : 0.f;
        float r1 = (k + 1 < H_) ? whh[j * H_ + k + 1] : 0.f;
        float z0 = (k < H_) ? whh[(100 + j) * H_ + k] : 0.f;
        float z1 = (k + 1 < H_) ? whh[(100 + j) * H_ + k + 1] : 0.f;
        float n0 = (k < H_) ? whh[(200 + j) * H_ + k] : 0.f;
        float n1 = (k + 1 < H_) ? whh[(200 + j) * H_ + k + 1] : 0.f;
        o[d]      = packh2(r0, r1);
        o[13 + d] = packh2(z0, z1);
        o[26 + d] = packh2(n0, n1);
    }
    o[39] = 0u;
}

// ---------------------------------------------------------------------------
// Scan matvec core.
// ---------------------------------------------------------------------------
#define LOAD_WREGS(WPBASE)                                                  \
    uint4 wq[10];                                                           \
    if (mv) {                                                               \
        const uint4* wp_ = (const uint4*)((WPBASE) + (size_t)tid * 40);     \
        _Pragma("unroll")                                                   \
        for (int i = 0; i < 10; ++i) wq[i] = wp_[i];                        \
    }

#define WD(i) (((i) & 3) == 0 ? wq[(i) >> 2].x : ((i) & 3) == 1 ? wq[(i) >> 2].y \
             : ((i) & 3) == 2 ? wq[(i) >> 2].z : wq[(i) >> 2].w)

#define MATVEC_REG(PBUF)                                                    \
    {                                                                       \
        const unsigned* hh = (const unsigned*)(PBUF);                       \
        _Pragma("unroll")                                                   \
        for (int d = 0; d < 13; ++d) {                                      \
            half2_t hv = u_as_h2(hh[13 * q + d]);                           \
            ar = __builtin_amdgcn_fdot2(u_as_h2(WD(d)),      hv, ar, false); \
            az = __builtin_amdgcn_fdot2(u_as_h2(WD(13 + d)), hv, az, false); \
            an = __builtin_amdgcn_fdot2(u_as_h2(WD(26 + d)), hv, an, false); \
        }                                                                   \
        ar += __shfl_xor(ar, 1); ar += __shfl_xor(ar, 2);                   \
        az += __shfl_xor(az, 1); az += __shfl_xor(az, 2);                   \
        an += __shfl_xor(an, 1); an += __shfl_xor(an, 2);                   \
    }

// ---------------------------------------------------------------------------
// K3: encoder scans. 512 blocks (4x redundant -> 2 blocks/CU; bid<128
// writes), 448 thr, 1 barrier/step, unroll-2 g prefetch.
// ---------------------------------------------------------------------------
#define ENCT 448
#define ENC_SUB(GA0, GA1, GA2, NB0, NB1, NB2, SC, SN)                       \
    {                                                                       \
        if (mv) {                                                           \
            if (q == 0 && (SN) < S_) {                                      \
                int tn_ = bwd ? (S_ - 1 - (SN)) : (SN);                     \
                const float* gg_ = gi + ((size_t)tn_ * B_ + b) * 600 + goff; \
                NB0 = gg_[j]; NB1 = gg_[100 + j]; NB2 = gg_[200 + j];       \
            }                                                               \
            float ar = 0.f, az = 0.f, an = 0.f;                             \
            MATVEC_REG(hhalf[p])                                            \
            if (q == 0) {                                                   \
                int tc_ = bwd ? (S_ - 1 - (SC)) : (SC);                     \
                float r = sigmoidf_(GA0 + ar + bhr);                        \
                float z = sigmoidf_(GA1 + az + bhz);                        \
                float n = tanhf_(GA2 + r * (an + bhn));                     \
                float hn = (1.f - z) * n + z * hc;                          \
                hc = hn;                                                    \
                hhalf[p ^ 1][j] = (_Float16)hn;                             \
                if (writer) out1[((size_t)tc_ * B_ + b) * 200 + ooff + j] = hn; \
            }                                                               \
        }                                                                   \
        __syncthreads();                                                    \
        p ^= 1;                                                             \
    }

__global__ __launch_bounds__(ENCT, 2) void enc_scan(
    const float* __restrict__ gi, const unsigned* __restrict__ wpack,
    const float* __restrict__ bhh_f, const float* __restrict__ bhh_b,
    float* __restrict__ out1, float* __restrict__ hT)
{
    __shared__ __align__(8) _Float16 hhalf[2][104];

    int bid = blockIdx.x;
    bool writer = bid < 128;
    int breal = bid & 127;
    int b = breal & 63;
    bool bwd = (breal >= 64);
    const float* bhh = bwd ? bhh_b : bhh_f;
    int tid = threadIdx.x;
    int j = tid >> 2, q = tid & 3;
    bool mv = tid < 400;
    const int goff = bwd ? G3 : 0;
    const int ooff = bwd ? H_ : 0;

    if (tid < 104) { hhalf[0][tid] = (_Float16)0.f; hhalf[1][tid] = (_Float16)0.f; }
    LOAD_WREGS(wpack + (bwd ? 16000 : 0))
    float bhr = 0.f, bhz = 0.f, bhn = 0.f, hc = 0.f;
    float pA0 = 0.f, pA1 = 0.f, pA2 = 0.f, pB0 = 0.f, pB1 = 0.f, pB2 = 0.f;
    if (mv && q == 0) {
        bhr = bhh[j]; bhz = bhh[100 + j]; bhn = bhh[200 + j];
        int t0 = bwd ? (S_ - 1) : 0;
        const float* gg = gi + ((size_t)t0 * B_ + b) * 600 + goff;
        pA0 = gg[j]; pA1 = gg[100 + j]; pA2 = gg[200 + j];
    }
    __syncthreads();

    int p = 0;
    for (int step = 0; step < S_; step += 2) {
        ENC_SUB(pA0, pA1, pA2, pB0, pB1, pB2, step, step + 1)
        ENC_SUB(pB0, pB1, pB2, pA0, pA1, pA2, step + 1, step + 2)
    }
    if (writer && !bwd && mv && q == 0) hT[b * H_ + j] = hc;
}

// ---------------------------------------------------------------------------
// K4a: W2[n] = dwih[n][50:150] @ l1w ; b2[n] ; tcg[c][n] = bih[n]+emb[c].dwih[n][0:50]
// ---------------------------------------------------------------------------
__global__ __launch_bounds__(256) void w2_precompute(
    const float* __restrict__ dwih, const float* __restrict__ l1w,
    const float* __restrict__ l1b, const float* __restrict__ emb,
    const float* __restrict__ bih,
    float* __restrict__ W2, float* __restrict__ b2, float* __restrict__ tcg)
{
    __shared__ float dw_s[H_];
    int n = blockIdx.x;
    int k = threadIdx.x;
    if (k < H_) dw_s[k] = dwih[(size_t)n * 150 + 50 + k];
    __syncthreads();
    if (k < 200) {
        float acc = 0.f;
        for (int i = 0; i < H_; ++i) acc += dw_s[i] * l1w[(size_t)i * 200 + k];
        W2[(size_t)n * 200 + k] = acc;
    } else if (k == 200) {
        float acc = 0.f;
        for (int i = 0; i < H_; ++i) acc += dw_s[i] * l1b[i];
        b2[n] = acc;
    } else if (k < 211) {
        int c = k - 201;
        float acc = bih[n];
        const float* er = emb + c * EMB_;
        const float* wr = dwih + (size_t)n * 150;
        for (int e = 0; e < EMB_; ++e) acc += er[e] * wr[e];
        tcg[c * G3 + n] = acc;
    }
}

// ---------------------------------------------------------------------------
// K5: decoder scan. 512 blocks (8x redundant -> 2 blocks/CU; bid<64
// writes), 448 thr, 1 barrier/step; argmax redundant per wave, softmax
// (exp/sum/log) only on the writer wave.
// ---------------------------------------------------------------------------
#define DECT 448
#define DEC_LOGITS(TPREV)                                                   \
    {                                                                       \
        float acc_ = 0.f;                                                   \
        if (lane < 40) {                                                    \
            int c_ = lane >> 2, part_ = lane & 3;                           \
            const float* hr_ = hl_s + c_ * H_;                              \
            const float* hv_ = hf[p];                                       \
            int k0_ = 25 * part_;                                           \
            for (int k_ = k0_; k_ < k0_ + 25; ++k_) acc_ += hr_[k_] * hv_[k_]; \
            acc_ += __shfl_xor(acc_, 1);                                    \
            acc_ += __shfl_xor(acc_, 2);                                    \
        }                                                                   \
        float src_ = __shfl(acc_, (lane < NC_) ? 4 * lane : 0);             \
        float lv_ = (lane < NC_) ? src_ + hlb_r : -INFINITY;                \
        float mx_ = lv_; int am_ = lane & 15;                               \
        _Pragma("unroll")                                                   \
        for (int m_ = 8; m_; m_ >>= 1) {                                    \
            float ov_ = __shfl_xor(mx_, m_);                                \
            int oa_ = __shfl_xor(am_, m_);                                  \
            if (ov_ > mx_ || (ov_ == mx_ && oa_ < am_)) { mx_ = ov_; am_ = oa_; } \
        }                                                                   \
        if (w0) {                                                           \
            float e_ = (lane < NC_) ? __expf(lv_ - mx_) : 0.f;              \
            float se_ = e_;                                                 \
            _Pragma("unroll")                                               \
            for (int m_ = 8; m_; m_ >>= 1) se_ += __shfl_xor(se_, m_);      \
            if (lane < NC_) {                                               \
                float lse_ = mx_ + __logf(se_);                             \
                out[((size_t)(TPREV) * B_ + b) * NC_ + lane] = lv_ - lse_;  \
            }                                                               \
        }                                                                   \
        prev = __shfl(am_, 0);                                              \
    }

#define DEC_SUB(GA0, GA1, GA2, NB0, NB1, NB2, TC)                           \
    {                                                                       \
        float ar = 0.f, az = 0.f, an = 0.f;                                 \
        if (mv && (TC) < S_) {                                              \
            if (q == 0 && (TC) + 1 < S_) {                                  \
                const float* gg_ = gi_lin + ((size_t)((TC) + 1) * B_ + b) * G3; \
                NB0 = gg_[j]; NB1 = gg_[100 + j]; NB2 = gg_[200 + j];       \
            }                                                               \
            MATVEC_REG(hhalf[p])                                            \
        }                                                                   \
        if ((TC) >= 1) DEC_LOGITS((TC) - 1)                                 \
        if (mv && (TC) < S_ && q == 0) {                                    \
            const float* tcp_ = tc_s + prev * G3;                           \
            float r = sigmoidf_(GA0 + tcp_[j]       + ar + bhr);            \
            float z = sigmoidf_(GA1 + tcp_[100 + j] + az + bhz);            \
            float n = tanhf_(   GA2 + tcp_[200 + j] + r * (an + bhn));      \
            float hn = (1.f - z) * n + z * hc;                              \
            hc = hn;                                                        \
            hf[p ^ 1][j] = hn;                                              \
            hhalf[p ^ 1][j] = (_Float16)hn;                                 \
        }                                                                   \
        __syncthreads();                                                    \
        p ^= 1;                                                             \
    }

__global__ __launch_bounds__(DECT, 2) void dec_scan(
    const float* __restrict__ gi_lin, const unsigned* __restrict__ wpack,
    const float* __restrict__ bhh, const float* __restrict__ tcg,
    const float* __restrict__ h2lw, const float* __restrict__ h2lb,
    const float* __restrict__ hT, float* __restrict__ out)
{
    __shared__ float tc_s[NC_ * G3];
    __shared__ float hl_s[NC_ * H_];
    __shared__ __align__(8) _Float16 hhalf[2][104];
    __shared__ __align__(16) float hf[2][104];

    int bid = blockIdx.x;
    bool writer = bid < 64;
    int b = bid & 63;
    int tid = threadIdx.x;
    int j = tid >> 2, q = tid & 3;
    bool mv = tid < 400;
    int lane = tid & 63;
    bool w0 = writer && (tid < 64);

    for (int idx = tid; idx < NC_ * G3; idx += DECT) tc_s[idx] = tcg[idx];
    for (int idx = tid; idx < NC_ * H_; idx += DECT) hl_s[idx] = h2lw[idx];
    if (tid < 104) {
        float hv = (tid < H_) ? hT[b * H_ + tid] : 0.f;
        hf[0][tid] = hv;            hf[1][tid] = 0.f;
        hhalf[0][tid] = (_Float16)hv; hhalf[1][tid] = (_Float16)0.f;
    }
    LOAD_WREGS(wpack + 32000)
    float bhr = 0.f, bhz = 0.f, bhn = 0.f, hc = 0.f;
    float pA0 = 0.f, pA1 = 0.f, pA2 = 0.f, pB0 = 0.f, pB1 = 0.f, pB2 = 0.f;
    if (mv && q == 0) {
        bhr = bhh[j]; bhz = bhh[100 + j]; bhn = bhh[200 + j];
        hc = hT[b * H_ + j];
        const float* gg = gi_lin + ((size_t)0 * B_ + b) * G3;
        pA0 = gg[j]; pA1 = gg[100 + j]; pA2 = gg[200 + j];
    }
    float hlb_r = (lane < NC_) ? h2lb[lane] : 0.f;
    int prev = 0;
    __syncthreads();

    int p = 0;
    DEC_SUB(pA0, pA1, pA2, pB0, pB1, pB2, 0)
    for (int it = 0; it < 16; ++it) {
        int tA = 2 * it + 1, tB = 2 * it + 2;
        DEC_SUB(pB0, pB1, pB2, pA0, pA1, pA2, tA)
        DEC_SUB(pA0, pA1, pA2, pB0, pB1, pB2, tB)
    }
}

// ---------------------------------------------------------------------------
extern "C" void kernel_launch(void* const* d_in, const int* in_sizes, int n_in,
                              void* d_out, int out_size, void* d_ws, size_t ws_size,
                              hipStream_t stream)
{
    const float* hs   = (const float*)d_in[0];
    const int*   cb   = (const int*)  d_in[1];
    const float* fc5w = (const float*)d_in[2];
    const float* fc5b = (const float*)d_in[3];
    const float* ewif = (const float*)d_in[4];
    const float* ewhf = (const float*)d_in[5];
    const float* ebif = (const float*)d_in[6];
    const float* ebhf = (const float*)d_in[7];
    const float* ewib = (const float*)d_in[8];
    const float* ewhb = (const float*)d_in[9];
    const float* ebib = (const float*)d_in[10];
    const float* ebhb = (const float*)d_in[11];
    const float* emb  = (const float*)d_in[12];
    const float* l1w  = (const float*)d_in[13];
    const float* l1b  = (const float*)d_in[14];
    const float* dwih = (const float*)d_in[15];
    const float* dwhh = (const float*)d_in[16];
    const float* dbih = (const float*)d_in[17];
    const float* dbhh = (const float*)d_in[18];
    const float* h2lw = (const float*)d_in[19];
    const float* h2lb = (const float*)d_in[20];
    float* out = (float*)d_out;

    float* ws   = (float*)d_ws;
    float* doc  = ws;                  // [32*64, 768]   = 1572864
    float* gi   = doc  + 1572864;      // [2048, 600]    = 1228800
    float* out1 = gi   + 1228800;      // [2048, 200]    = 409600
    float* hT   = out1 + 409600;       // [64, 100]      = 6400
    float* W2   = hT   + 6400;         // [300, 200]     = 60000
    float* b2   = W2   + 60000;        // [300]
    float* tcg  = b2   + 320;          // [10, 300]      = 3000
    float* gil  = tcg  + 3072;         // [2048, 300]    = 614400
    unsigned* wpack = (unsigned*)(gil + 614400);  // 3 * 16000 dwords

    pool_kernel<<<dim3(S_, B_), 256, 0, stream>>>(hs, cb, fc5w, fc5b, doc);
    w2_precompute<<<G3, 256, 0, stream>>>(dwih, l1w, l1b, emb, dbih, W2, b2, tcg);
    pack_whh<<<3, 400, 0, stream>>>(ewhf, ewhb, dwhh, wpack);
    gemm_enc<<<dim3(10, 32), 256, 0, stream>>>(doc, ewif, ewib, ebif, ebib, gi);
    enc_scan<<<512, ENCT, 0, stream>>>(gi, wpack, ebhf, ebhb, out1, hT);
    gemm_gil<<<dim3(5, 32), 256, 0, stream>>>(out1, W2, b2, gil);
    dec_scan<<<512, DECT, 0, stream>>>(gil, wpack, dbhh, tcg,
                                       h2lw, h2lb, hT, out);
}

// Round 16
// 176.804 us; speedup vs baseline: 1.1589x; 1.1589x over previous
//
#include <hip/hip_runtime.h>
#include <hip/hip_bf16.h>
#include <math.h>

#define B_ 64
#define L_ 512
#define D_ 768
#define J_ 31
#define S_ 32
#define H_ 100
#define G3 300
#define NC_ 10
#define EMB_ 50

__device__ __forceinline__ float sigmoidf_(float x) { return 1.0f / (1.0f + __expf(-x)); }
__device__ __forceinline__ float tanhf_(float x) {
    float e = __expf(2.0f * x);
    return 1.0f - 2.0f / (e + 1.0f);
}
__device__ __forceinline__ float dot4f_(float4 a, float4 b) {
    return a.x * b.x + a.y * b.y + a.z * b.z + a.w * b.w;
}

typedef _Float16 half2_t __attribute__((ext_vector_type(2)));
__device__ __forceinline__ half2_t u_as_h2(unsigned u) { return __builtin_bit_cast(half2_t, u); }
__device__ __forceinline__ unsigned packh2(float a, float b) {
    half2_t p; p.x = (_Float16)a; p.y = (_Float16)b;
    return __builtin_bit_cast(unsigned, p);
}

// ---------------------------------------------------------------------------
// K1: per-clause pooling — single-pass online softmax, one barrier.
// ---------------------------------------------------------------------------
__global__ __launch_bounds__(256) void pool_kernel(
    const float* __restrict__ hs, const int* __restrict__ cb,
    const float* __restrict__ fc5w, const float* __restrict__ fc5b,
    float* __restrict__ doc)
{
    __shared__ __align__(16) float acc_s[4][D_];
    __shared__ float m_s[4], l_s[4];

    int s = blockIdx.x, b = blockIdx.y;
    int start = (s == 0) ? 0 : cb[b * J_ + s - 1];
    int end   = (s == J_) ? L_ : cb[b * J_ + s];
    int nt = end - start;
    int tid = threadIdx.x;
    int lane = tid & 63, wv = tid >> 6;

    if (nt <= 0) {
        for (int d = tid; d < D_; d += 256) doc[((size_t)s * B_ + b) * D_ + d] = 0.f;
        return;
    }

    float4 fwv[3];
#pragma unroll
    for (int i = 0; i < 3; ++i)
        fwv[i] = *(const float4*)(fc5w + 4 * lane + 256 * i);
    float bias = fc5b[0];

    const float* base = hs + ((size_t)b * L_ + start) * D_;
    float m = -INFINITY, l = 0.f;
    float4 acc[3];
#pragma unroll
    for (int i = 0; i < 3; ++i) acc[i] = make_float4(0.f, 0.f, 0.f, 0.f);

    for (int t = wv; t < nt; t += 4) {
        const float* row = base + (size_t)t * D_;
        float4 x0 = *(const float4*)(row + 4 * lane);
        float4 x1 = *(const float4*)(row + 4 * lane + 256);
        float4 x2 = *(const float4*)(row + 4 * lane + 512);
        float p = dot4f_(x0, fwv[0]) + dot4f_(x1, fwv[1]) + dot4f_(x2, fwv[2]);
#pragma unroll
        for (int off = 32; off; off >>= 1) p += __shfl_xor(p, off);
        p += bias;
        if (p > m) {
            float sc = __expf(m - p);
            l *= sc;
#pragma unroll
            for (int i = 0; i < 3; ++i) {
                acc[i].x *= sc; acc[i].y *= sc; acc[i].z *= sc; acc[i].w *= sc;
            }
            m = p;
        }
        float e = __expf(p - m);
        l += e;
        acc[0].x += e * x0.x; acc[0].y += e * x0.y; acc[0].z += e * x0.z; acc[0].w += e * x0.w;
        acc[1].x += e * x1.x; acc[1].y += e * x1.y; acc[1].z += e * x1.z; acc[1].w += e * x1.w;
        acc[2].x += e * x2.x; acc[2].y += e * x2.y; acc[2].z += e * x2.z; acc[2].w += e * x2.w;
    }
#pragma unroll
    for (int i = 0; i < 3; ++i)
        *(float4*)&acc_s[wv][4 * lane + 256 * i] = acc[i];
    if (lane == 0) { m_s[wv] = m; l_s[wv] = l; }
    __syncthreads();

    float M = fmaxf(fmaxf(m_s[0], m_s[1]), fmaxf(m_s[2], m_s[3]));
    float f0 = (l_s[0] > 0.f) ? __expf(m_s[0] - M) : 0.f;
    float f1 = (l_s[1] > 0.f) ? __expf(m_s[1] - M) : 0.f;
    float f2 = (l_s[2] > 0.f) ? __expf(m_s[2] - M) : 0.f;
    float f3 = (l_s[3] > 0.f) ? __expf(m_s[3] - M) : 0.f;
    float inv = 1.f / (l_s[0] * f0 + l_s[1] * f1 + l_s[2] * f2 + l_s[3] * f3);
    float* o = doc + ((size_t)s * B_ + b) * D_;
#pragma unroll
    for (int i = 0; i < 3; ++i) {
        int d = tid + 256 * i;
        float num = acc_s[0][d] * f0 + acc_s[1][d] * f1
                  + acc_s[2][d] * f2 + acc_s[3][d] * f3;
        o[d] = num * inv;
    }
}

// ---------------------------------------------------------------------------
// K2: gi = doc @ [Wf;Wb].T + bias via f16 dot2 (pack during staging).
// ---------------------------------------------------------------------------
__global__ __launch_bounds__(256) void gemm_enc(
    const float* __restrict__ A,
    const float* __restrict__ Wf, const float* __restrict__ Wb,
    const float* __restrict__ bf_, const float* __restrict__ bb_,
    float* __restrict__ C)
{
    __shared__ __align__(16) unsigned As[16][68];
    __shared__ __align__(16) unsigned Ws[16][68];
    int n0 = blockIdx.x * 64, m0 = blockIdx.y * 64;
    int tid = threadIdx.x;
    int tx = tid & 15, ty = tid >> 4;
    int lr = tid >> 2, lk4 = tid & 3;
    float acc[4][4] = {};

    for (int kk = 0; kk < 384; kk += 16) {
        {
            const float* ap = A + ((size_t)(m0 + lr)) * D_ + (kk + lk4 * 4) * 2;
            float4 x = *(const float4*)ap;
            float4 y = *(const float4*)(ap + 4);
            As[lk4 * 4 + 0][lr] = packh2(x.x, x.y);
            As[lk4 * 4 + 1][lr] = packh2(x.z, x.w);
            As[lk4 * 4 + 2][lr] = packh2(y.x, y.y);
            As[lk4 * 4 + 3][lr] = packh2(y.z, y.w);
            int n = n0 + lr;
            float4 u = make_float4(0.f, 0.f, 0.f, 0.f);
            float4 v = make_float4(0.f, 0.f, 0.f, 0.f);
            if (n < G3) {
                const float* wp = Wf + (size_t)n * D_ + (kk + lk4 * 4) * 2;
                u = *(const float4*)wp; v = *(const float4*)(wp + 4);
            } else if (n < 600) {
                const float* wp = Wb + (size_t)(n - G3) * D_ + (kk + lk4 * 4) * 2;
                u = *(const float4*)wp; v = *(const float4*)(wp + 4);
            }
            Ws[lk4 * 4 + 0][lr] = packh2(u.x, u.y);
            Ws[lk4 * 4 + 1][lr] = packh2(u.z, u.w);
            Ws[lk4 * 4 + 2][lr] = packh2(v.x, v.y);
            Ws[lk4 * 4 + 3][lr] = packh2(v.z, v.w);
        }
        __syncthreads();
#pragma unroll
        for (int ku = 0; ku < 16; ++ku) {
            uint4 av = *(const uint4*)&As[ku][ty * 4];
            uint4 wv = *(const uint4*)&Ws[ku][tx * 4];
            unsigned aa[4] = {av.x, av.y, av.z, av.w};
            unsigned ww[4] = {wv.x, wv.y, wv.z, wv.w};
#pragma unroll
            for (int i = 0; i < 4; ++i)
#pragma unroll
                for (int jj = 0; jj < 4; ++jj)
                    acc[i][jj] = __builtin_amdgcn_fdot2(u_as_h2(aa[i]), u_as_h2(ww[jj]),
                                                        acc[i][jj], false);
        }
        __syncthreads();
    }
#pragma unroll
    for (int jj = 0; jj < 4; ++jj) {
        int n = n0 + tx * 4 + jj;
        if (n >= 600) continue;
        float bias = (n < G3) ? bf_[n] : bb_[n - G3];
#pragma unroll
        for (int i = 0; i < 4; ++i) {
            int m = m0 + ty * 4 + i;
            C[(size_t)m * 600 + n] = acc[i][jj] + bias;
        }
    }
}

// ---------------------------------------------------------------------------
// K2b: gil = out1 @ W2.T + b2.  M=2048, N=300, K=200, f32 64x64 tiles.
// ---------------------------------------------------------------------------
__global__ __launch_bounds__(256) void gemm_gil(
    const float* __restrict__ A, const float* __restrict__ W,
    const float* __restrict__ bias, float* __restrict__ C)
{
    __shared__ __align__(16) float As[16][68];
    __shared__ __align__(16) float Ws[16][68];
    int n0 = blockIdx.x * 64, m0 = blockIdx.y * 64;
    int tid = threadIdx.x;
    int tx = tid & 15, ty = tid >> 4;
    int lr = tid >> 2, lk4 = tid & 3;
    float acc[4][4] = {};

    for (int kk = 0; kk < 208; kk += 16) {
        int k = kk + lk4 * 4;
        float4 av = make_float4(0.f, 0.f, 0.f, 0.f);
        if (k < 200) av = *(const float4*)(A + (size_t)(m0 + lr) * 200 + k);
        As[lk4 * 4 + 0][lr] = av.x; As[lk4 * 4 + 1][lr] = av.y;
        As[lk4 * 4 + 2][lr] = av.z; As[lk4 * 4 + 3][lr] = av.w;
        int n = n0 + lr;
        float4 wv = make_float4(0.f, 0.f, 0.f, 0.f);
        if (n < G3 && k < 200) wv = *(const float4*)(W + (size_t)n * 200 + k);
        Ws[lk4 * 4 + 0][lr] = wv.x; Ws[lk4 * 4 + 1][lr] = wv.y;
        Ws[lk4 * 4 + 2][lr] = wv.z; Ws[lk4 * 4 + 3][lr] = wv.w;
        __syncthreads();
#pragma unroll
        for (int ki = 0; ki < 16; ++ki) {
            float4 a4 = *(const float4*)&As[ki][ty * 4];
            float4 w4 = *(const float4*)&Ws[ki][tx * 4];
            float ai[4] = {a4.x, a4.y, a4.z, a4.w};
            float wj[4] = {w4.x, w4.y, w4.z, w4.w};
#pragma unroll
            for (int i = 0; i < 4; ++i)
#pragma unroll
                for (int jj = 0; jj < 4; ++jj) acc[i][jj] += ai[i] * wj[jj];
        }
        __syncthreads();
    }
#pragma unroll
    for (int jj = 0; jj < 4; ++jj) {
        int n = n0 + tx * 4 + jj;
        if (n >= G3) continue;
#pragma unroll
        for (int i = 0; i < 4; ++i) {
            int m = m0 + ty * 4 + i;
            C[(size_t)m * G3 + n] = acc[i][jj] + bias[n];
        }
    }
}

// ---------------------------------------------------------------------------
// Kpack: per-thread-contiguous packed-f16 Whh for the scans.
// ---------------------------------------------------------------------------
__global__ __launch_bounds__(400) void pack_whh(
    const float* __restrict__ wf, const float* __restrict__ wb,
    const float* __restrict__ wd, unsigned* __restrict__ wpack)
{
    int m = blockIdx.x;
    const float* whh = (m == 0) ? wf : (m == 1) ? wb : wd;
    int tid = threadIdx.x;
    int j = tid >> 2, q = tid & 3;
    unsigned* o = wpack + (size_t)m * 16000 + (size_t)tid * 40;
#pragma unroll
    for (int d = 0; d < 13; ++d) {
        int k = 2 * (13 * q + d);
        float r0 = (k < H_) ? whh[j * H_ + k] : 0.f;
        float r1 = (k + 1 < H_) ? whh[j * H_ + k + 1] : 0.f;
        float z0 = (k < H_) ? whh[(100 + j) * H_ + k] : 0.f;
        float z1 = (k + 1 < H_) ? whh[(100 + j) * H_ + k + 1] : 0.f;
        float n0 = (k < H_) ? whh[(200 + j) * H_ + k] : 0.f;
        float n1 = (k + 1 < H_) ? whh[(200 + j) * H_ + k + 1] : 0.f;
        o[d]      = packh2(r0, r1);
        o[13 + d] = packh2(z0, z1);
        o[26 + d] = packh2(n0, n1);
    }
    o[39] = 0u;
}

// ---------------------------------------------------------------------------
// Scan matvec core.
// ---------------------------------------------------------------------------
#define LOAD_WREGS(WPBASE)                                                  \
    uint4 wq[10];                                                           \
    if (mv) {                                                               \
        const uint4* wp_ = (const uint4*)((WPBASE) + (size_t)tid * 40);     \
        _Pragma("unroll")                                                   \
        for (int i = 0; i < 10; ++i) wq[i] = wp_[i];                        \
    }

#define WD(i) (((i) & 3) == 0 ? wq[(i) >> 2].x : ((i) & 3) == 1 ? wq[(i) >> 2].y \
             : ((i) & 3) == 2 ? wq[(i) >> 2].z : wq[(i) >> 2].w)

#define MATVEC_REG(PBUF)                                                    \
    {                                                                       \
        const unsigned* hh = (const unsigned*)(PBUF);                       \
        _Pragma("unroll")                                                   \
        for (int d = 0; d < 13; ++d) {                                      \
            half2_t hv = u_as_h2(hh[13 * q + d]);                           \
            ar = __builtin_amdgcn_fdot2(u_as_h2(WD(d)),      hv, ar, false); \
            az = __builtin_amdgcn_fdot2(u_as_h2(WD(13 + d)), hv, az, false); \
            an = __builtin_amdgcn_fdot2(u_as_h2(WD(26 + d)), hv, an, false); \
        }                                                                   \
        ar += __shfl_xor(ar, 1); ar += __shfl_xor(ar, 2);                   \
        az += __shfl_xor(az, 1); az += __shfl_xor(az, 2);                   \
        an += __shfl_xor(an, 1); an += __shfl_xor(an, 2);                   \
    }

// ---------------------------------------------------------------------------
// K3: encoder scans. 128 blocks = (b, dir) writers only, 448 thr,
// 1 barrier/step, unroll-2 g prefetch.
// ---------------------------------------------------------------------------
#define ENCT 448
#define ENC_SUB(GA0, GA1, GA2, NB0, NB1, NB2, SC, SN)                       \
    {                                                                       \
        if (mv) {                                                           \
            if (q == 0 && (SN) < S_) {                                      \
                int tn_ = bwd ? (S_ - 1 - (SN)) : (SN);                     \
                const float* gg_ = gi + ((size_t)tn_ * B_ + b) * 600 + goff; \
                NB0 = gg_[j]; NB1 = gg_[100 + j]; NB2 = gg_[200 + j];       \
            }                                                               \
            float ar = 0.f, az = 0.f, an = 0.f;                             \
            MATVEC_REG(hhalf[p])                                            \
            if (q == 0) {                                                   \
                int tc_ = bwd ? (S_ - 1 - (SC)) : (SC);                     \
                float r = sigmoidf_(GA0 + ar + bhr);                        \
                float z = sigmoidf_(GA1 + az + bhz);                        \
                float n = tanhf_(GA2 + r * (an + bhn));                     \
                float hn = (1.f - z) * n + z * hc;                          \
                hc = hn;                                                    \
                hhalf[p ^ 1][j] = (_Float16)hn;                             \
                out1[((size_t)tc_ * B_ + b) * 200 + ooff + j] = hn;         \
            }                                                               \
        }                                                                   \
        __syncthreads();                                                    \
        p ^= 1;                                                             \
    }

__global__ __launch_bounds__(ENCT, 1) void enc_scan(
    const float* __restrict__ gi, const unsigned* __restrict__ wpack,
    const float* __restrict__ bhh_f, const float* __restrict__ bhh_b,
    float* __restrict__ out1, float* __restrict__ hT)
{
    __shared__ __align__(8) _Float16 hhalf[2][104];

    int bid = blockIdx.x;
    int b = bid & 63;
    bool bwd = (bid >= 64);
    const float* bhh = bwd ? bhh_b : bhh_f;
    int tid = threadIdx.x;
    int j = tid >> 2, q = tid & 3;
    bool mv = tid < 400;
    const int goff = bwd ? G3 : 0;
    const int ooff = bwd ? H_ : 0;

    if (tid < 104) { hhalf[0][tid] = (_Float16)0.f; hhalf[1][tid] = (_Float16)0.f; }
    LOAD_WREGS(wpack + (bwd ? 16000 : 0))
    float bhr = 0.f, bhz = 0.f, bhn = 0.f, hc = 0.f;
    float pA0 = 0.f, pA1 = 0.f, pA2 = 0.f, pB0 = 0.f, pB1 = 0.f, pB2 = 0.f;
    if (mv && q == 0) {
        bhr = bhh[j]; bhz = bhh[100 + j]; bhn = bhh[200 + j];
        int t0 = bwd ? (S_ - 1) : 0;
        const float* gg = gi + ((size_t)t0 * B_ + b) * 600 + goff;
        pA0 = gg[j]; pA1 = gg[100 + j]; pA2 = gg[200 + j];
    }
    __syncthreads();

    int p = 0;
    for (int step = 0; step < S_; step += 2) {
        ENC_SUB(pA0, pA1, pA2, pB0, pB1, pB2, step, step + 1)
        ENC_SUB(pB0, pB1, pB2, pA0, pA1, pA2, step + 1, step + 2)
    }
    if (!bwd && mv && q == 0) hT[b * H_ + j] = hc;
}

// ---------------------------------------------------------------------------
// K4a: W2[n] = dwih[n][50:150] @ l1w ; b2[n] ; tcg[c][n] = bih[n]+emb[c].dwih[n][0:50]
// ---------------------------------------------------------------------------
__global__ __launch_bounds__(256) void w2_precompute(
    const float* __restrict__ dwih, const float* __restrict__ l1w,
    const float* __restrict__ l1b, const float* __restrict__ emb,
    const float* __restrict__ bih,
    float* __restrict__ W2, float* __restrict__ b2, float* __restrict__ tcg)
{
    __shared__ float dw_s[H_];
    int n = blockIdx.x;
    int k = threadIdx.x;
    if (k < H_) dw_s[k] = dwih[(size_t)n * 150 + 50 + k];
    __syncthreads();
    if (k < 200) {
        float acc = 0.f;
        for (int i = 0; i < H_; ++i) acc += dw_s[i] * l1w[(size_t)i * 200 + k];
        W2[(size_t)n * 200 + k] = acc;
    } else if (k == 200) {
        float acc = 0.f;
        for (int i = 0; i < H_; ++i) acc += dw_s[i] * l1b[i];
        b2[n] = acc;
    } else if (k < 211) {
        int c = k - 201;
        float acc = bih[n];
        const float* er = emb + c * EMB_;
        const float* wr = dwih + (size_t)n * 150;
        for (int e = 0; e < EMB_; ++e) acc += er[e] * wr[e];
        tcg[c * G3 + n] = acc;
    }
}

// ---------------------------------------------------------------------------
// K5: decoder scan. 64 blocks (writers only), 448 thr, 1 barrier/step;
// argmax redundant per wave, softmax (exp/sum/log) only on wave 0.
// ---------------------------------------------------------------------------
#define DECT 448
#define DEC_LOGITS(TPREV)                                                   \
    {                                                                       \
        float acc_ = 0.f;                                                   \
        if (lane < 40) {                                                    \
            int c_ = lane >> 2, part_ = lane & 3;                           \
            const float* hr_ = hl_s + c_ * H_;                              \
            const float* hv_ = hf[p];                                       \
            int k0_ = 25 * part_;                                           \
            for (int k_ = k0_; k_ < k0_ + 25; ++k_) acc_ += hr_[k_] * hv_[k_]; \
            acc_ += __shfl_xor(acc_, 1);                                    \
            acc_ += __shfl_xor(acc_, 2);                                    \
        }                                                                   \
        float src_ = __shfl(acc_, (lane < NC_) ? 4 * lane : 0);             \
        float lv_ = (lane < NC_) ? src_ + hlb_r : -INFINITY;                \
        float mx_ = lv_; int am_ = lane & 15;                               \
        _Pragma("unroll")                                                   \
        for (int m_ = 8; m_; m_ >>= 1) {                                    \
            float ov_ = __shfl_xor(mx_, m_);                                \
            int oa_ = __shfl_xor(am_, m_);                                  \
            if (ov_ > mx_ || (ov_ == mx_ && oa_ < am_)) { mx_ = ov_; am_ = oa_; } \
        }                                                                   \
        if (w0) {                                                           \
            float e_ = (lane < NC_) ? __expf(lv_ - mx_) : 0.f;              \
            float se_ = e_;                                                 \
            _Pragma("unroll")                                               \
            for (int m_ = 8; m_; m_ >>= 1) se_ += __shfl_xor(se_, m_);      \
            if (lane < NC_) {                                               \
                float lse_ = mx_ + __logf(se_);                             \
                out[((size_t)(TPREV) * B_ + b) * NC_ + lane] = lv_ - lse_;  \
            }                                                               \
        }                                                                   \
        prev = __shfl(am_, 0);                                              \
    }

#define DEC_SUB(GA0, GA1, GA2, NB0, NB1, NB2, TC)                           \
    {                                                                       \
        float ar = 0.f, az = 0.f, an = 0.f;                                 \
        if (mv && (TC) < S_) {                                              \
            if (q == 0 && (TC) + 1 < S_) {                                  \
                const float* gg_ = gi_lin + ((size_t)((TC) + 1) * B_ + b) * G3; \
                NB0 = gg_[j]; NB1 = gg_[100 + j]; NB2 = gg_[200 + j];       \
            }                                                               \
            MATVEC_REG(hhalf[p])                                            \
        }                                                                   \
        if ((TC) >= 1) DEC_LOGITS((TC) - 1)                                 \
        if (mv && (TC) < S_ && q == 0) {                                    \
            const float* tcp_ = tc_s + prev * G3;                           \
            float r = sigmoidf_(GA0 + tcp_[j]       + ar + bhr);            \
            float z = sigmoidf_(GA1 + tcp_[100 + j] + az + bhz);            \
            float n = tanhf_(   GA2 + tcp_[200 + j] + r * (an + bhn));      \
            float hn = (1.f - z) * n + z * hc;                              \
            hc = hn;                                                        \
            hf[p ^ 1][j] = hn;                                              \
            hhalf[p ^ 1][j] = (_Float16)hn;                                 \
        }                                                                   \
        __syncthreads();                                                    \
        p ^= 1;                                                             \
    }

__global__ __launch_bounds__(DECT, 1) void dec_scan(
    const float* __restrict__ gi_lin, const unsigned* __restrict__ wpack,
    const float* __restrict__ bhh, const float* __restrict__ tcg,
    const float* __restrict__ h2lw, const float* __restrict__ h2lb,
    const float* __restrict__ hT, float* __restrict__ out)
{
    __shared__ float tc_s[NC_ * G3];
    __shared__ float hl_s[NC_ * H_];
    __shared__ __align__(8) _Float16 hhalf[2][104];
    __shared__ __align__(16) float hf[2][104];

    int bid = blockIdx.x;
    int b = bid & 63;
    int tid = threadIdx.x;
    int j = tid >> 2, q = tid & 3;
    bool mv = tid < 400;
    int lane = tid & 63;
    bool w0 = (tid < 64);

    for (int idx = tid; idx < NC_ * G3; idx += DECT) tc_s[idx] = tcg[idx];
    for (int idx = tid; idx < NC_ * H_; idx += DECT) hl_s[idx] = h2lw[idx];
    if (tid < 104) {
        float hv = (tid < H_) ? hT[b * H_ + tid] : 0.f;
        hf[0][tid] = hv;            hf[1][tid] = 0.f;
        hhalf[0][tid] = (_Float16)hv; hhalf[1][tid] = (_Float16)0.f;
    }
    LOAD_WREGS(wpack + 32000)
    float bhr = 0.f, bhz = 0.f, bhn = 0.f, hc = 0.f;
    float pA0 = 0.f, pA1 = 0.f, pA2 = 0.f, pB0 = 0.f, pB1 = 0.f, pB2 = 0.f;
    if (mv && q == 0) {
        bhr = bhh[j]; bhz = bhh[100 + j]; bhn = bhh[200 + j];
        hc = hT[b * H_ + j];
        const float* gg = gi_lin + ((size_t)0 * B_ + b) * G3;
        pA0 = gg[j]; pA1 = gg[100 + j]; pA2 = gg[200 + j];
    }
    float hlb_r = (lane < NC_) ? h2lb[lane] : 0.f;
    int prev = 0;
    __syncthreads();

    int p = 0;
    DEC_SUB(pA0, pA1, pA2, pB0, pB1, pB2, 0)
    for (int it = 0; it < 16; ++it) {
        int tA = 2 * it + 1, tB = 2 * it + 2;
        DEC_SUB(pB0, pB1, pB2, pA0, pA1, pA2, tA)
        DEC_SUB(pA0, pA1, pA2, pB0, pB1, pB2, tB)
    }
}

// ---------------------------------------------------------------------------
extern "C" void kernel_launch(void* const* d_in, const int* in_sizes, int n_in,
                              void* d_out, int out_size, void* d_ws, size_t ws_size,
                              hipStream_t stream)
{
    const float* hs   = (const float*)d_in[0];
    const int*   cb   = (const int*)  d_in[1];
    const float* fc5w = (const float*)d_in[2];
    const float* fc5b = (const float*)d_in[3];
    const float* ewif = (const float*)d_in[4];
    const float* ewhf = (const float*)d_in[5];
    const float* ebif = (const float*)d_in[6];
    const float* ebhf = (const float*)d_in[7];
    const float* ewib = (const float*)d_in[8];
    const float* ewhb = (const float*)d_in[9];
    const float* ebib = (const float*)d_in[10];
    const float* ebhb = (const float*)d_in[11];
    const float* emb  = (const float*)d_in[12];
    const float* l1w  = (const float*)d_in[13];
    const float* l1b  = (const float*)d_in[14];
    const float* dwih = (const float*)d_in[15];
    const float* dwhh = (const float*)d_in[16];
    const float* dbih = (const float*)d_in[17];
    const float* dbhh = (const float*)d_in[18];
    const float* h2lw = (const float*)d_in[19];
    const float* h2lb = (const float*)d_in[20];
    float* out = (float*)d_out;

    float* ws   = (float*)d_ws;
    float* doc  = ws;                  // [32*64, 768]   = 1572864
    float* gi   = doc  + 1572864;      // [2048, 600]    = 1228800
    float* out1 = gi   + 1228800;      // [2048, 200]    = 409600
    float* hT   = out1 + 409600;       // [64, 100]      = 6400
    float* W2   = hT   + 6400;         // [300, 200]     = 60000
    float* b2   = W2   + 60000;        // [300]
    float* tcg  = b2   + 320;          // [10, 300]      = 3000
    float* gil  = tcg  + 3072;         // [2048, 300]    = 614400
    unsigned* wpack = (unsigned*)(gil + 614400);  // 3 * 16000 dwords

    pool_kernel<<<dim3(S_, B_), 256, 0, stream>>>(hs, cb, fc5w, fc5b, doc);
    w2_precompute<<<G3, 256, 0, stream>>>(dwih, l1w, l1b, emb, dbih, W2, b2, tcg);
    pack_whh<<<3, 400, 0, stream>>>(ewhf, ewhb, dwhh, wpack);
    gemm_enc<<<dim3(10, 32), 256, 0, stream>>>(doc, ewif, ewib, ebif, ebib, gi);
    enc_scan<<<128, ENCT, 0, stream>>>(gi, wpack, ebhf, ebhb, out1, hT);
    gemm_gil<<<dim3(5, 32), 256, 0, stream>>>(out1, W2, b2, gil);
    dec_scan<<<64, DECT, 0, stream>>>(gil, wpack, dbhh, tcg,
                                      h2lw, h2lb, hT, out);
}

// Round 17
// 169.423 us; speedup vs baseline: 1.2094x; 1.0436x over previous
//
#include <hip/hip_runtime.h>
#include <hip/hip_bf16.h>
#include <math.h>

#define B_ 64
#define L_ 512
#define D_ 768
#define J_ 31
#define S_ 32
#define H_ 100
#define G3 300
#define NC_ 10
#define EMB_ 50

__device__ __forceinline__ float sigmoidf_(float x) { return 1.0f / (1.0f + __expf(-x)); }
__device__ __forceinline__ float tanhf_(float x) {
    float e = __expf(2.0f * x);
    return 1.0f - 2.0f / (e + 1.0f);
}
__device__ __forceinline__ float dot4f_(float4 a, float4 b) {
    return a.x * b.x + a.y * b.y + a.z * b.z + a.w * b.w;
}

typedef _Float16 half2_t __attribute__((ext_vector_type(2)));
__device__ __forceinline__ half2_t u_as_h2(unsigned u) { return __builtin_bit_cast(half2_t, u); }
__device__ __forceinline__ unsigned packh2(float a, float b) {
    half2_t p; p.x = (_Float16)a; p.y = (_Float16)b;
    return __builtin_bit_cast(unsigned, p);
}

// ---------------------------------------------------------------------------
// K1: fused pool + prep.  Blocks 0..2047: per-clause online-softmax pooling
// (s = bid>>6, b = bid&63).  Blocks 2048..2347: w2/b2/tcg precompute
// (n = bid-2048).  Blocks 2348..2350: pack_whh (m = bid-2348).
// Prep work hides entirely under the 2048 pool blocks.
// ---------------------------------------------------------------------------
__global__ __launch_bounds__(256) void pool_prep_kernel(
    const float* __restrict__ hs, const int* __restrict__ cb,
    const float* __restrict__ fc5w, const float* __restrict__ fc5b,
    float* __restrict__ doc,
    const float* __restrict__ dwih, const float* __restrict__ l1w,
    const float* __restrict__ l1b, const float* __restrict__ emb,
    const float* __restrict__ bih,
    float* __restrict__ W2, float* __restrict__ b2, float* __restrict__ tcg,
    const float* __restrict__ ewhf, const float* __restrict__ ewhb,
    const float* __restrict__ dwhh, unsigned* __restrict__ wpack)
{
    __shared__ __align__(16) float acc_s[4][D_];
    __shared__ float m_s[4], l_s[4];

    int bidx = blockIdx.x;
    int tid = threadIdx.x;

    if (bidx >= 2048) {
        if (bidx < 2348) {
            // ---- w2_precompute for row n ----
            int n = bidx - 2048;
            __shared__ float dw_s[H_];
            int k = tid;
            if (k < H_) dw_s[k] = dwih[(size_t)n * 150 + 50 + k];
            __syncthreads();
            if (k < 200) {
                float acc = 0.f;
                for (int i = 0; i < H_; ++i) acc += dw_s[i] * l1w[(size_t)i * 200 + k];
                W2[(size_t)n * 200 + k] = acc;
            } else if (k == 200) {
                float acc = 0.f;
                for (int i = 0; i < H_; ++i) acc += dw_s[i] * l1b[i];
                b2[n] = acc;
            } else if (k < 211) {
                int c = k - 201;
                float acc = bih[n];
                const float* er = emb + c * EMB_;
                const float* wr = dwih + (size_t)n * 150;
                for (int e = 0; e < EMB_; ++e) acc += er[e] * wr[e];
                tcg[c * G3 + n] = acc;
            }
        } else {
            // ---- pack_whh for matrix m ----
            int m = bidx - 2348;
            const float* whh = (m == 0) ? ewhf : (m == 1) ? ewhb : dwhh;
            for (int t = tid; t < 400; t += 256) {
                int j = t >> 2, q = t & 3;
                unsigned* o = wpack + (size_t)m * 16000 + (size_t)t * 40;
#pragma unroll
                for (int d = 0; d < 13; ++d) {
                    int k = 2 * (13 * q + d);
                    float r0 = (k < H_) ? whh[j * H_ + k] : 0.f;
                    float r1 = (k + 1 < H_) ? whh[j * H_ + k + 1] : 0.f;
                    float z0 = (k < H_) ? whh[(100 + j) * H_ + k] : 0.f;
                    float z1 = (k + 1 < H_) ? whh[(100 + j) * H_ + k + 1] : 0.f;
                    float n0 = (k < H_) ? whh[(200 + j) * H_ + k] : 0.f;
                    float n1 = (k + 1 < H_) ? whh[(200 + j) * H_ + k + 1] : 0.f;
                    o[d]      = packh2(r0, r1);
                    o[13 + d] = packh2(z0, z1);
                    o[26 + d] = packh2(n0, n1);
                }
                o[39] = 0u;
            }
        }
        return;
    }

    // ---- pooling for (s, b) ----
    int s = bidx >> 6, b = bidx & 63;
    int start = (s == 0) ? 0 : cb[b * J_ + s - 1];
    int end   = (s == J_) ? L_ : cb[b * J_ + s];
    int nt = end - start;
    int lane = tid & 63, wv = tid >> 6;

    if (nt <= 0) {
        for (int d = tid; d < D_; d += 256) doc[((size_t)s * B_ + b) * D_ + d] = 0.f;
        return;
    }

    float4 fwv[3];
#pragma unroll
    for (int i = 0; i < 3; ++i)
        fwv[i] = *(const float4*)(fc5w + 4 * lane + 256 * i);
    float bias = fc5b[0];

    const float* base = hs + ((size_t)b * L_ + start) * D_;
    float m = -INFINITY, l = 0.f;
    float4 acc[3];
#pragma unroll
    for (int i = 0; i < 3; ++i) acc[i] = make_float4(0.f, 0.f, 0.f, 0.f);

    for (int t = wv; t < nt; t += 4) {
        const float* row = base + (size_t)t * D_;
        float4 x0 = *(const float4*)(row + 4 * lane);
        float4 x1 = *(const float4*)(row + 4 * lane + 256);
        float4 x2 = *(const float4*)(row + 4 * lane + 512);
        float p = dot4f_(x0, fwv[0]) + dot4f_(x1, fwv[1]) + dot4f_(x2, fwv[2]);
#pragma unroll
        for (int off = 32; off; off >>= 1) p += __shfl_xor(p, off);
        p += bias;
        if (p > m) {
            float sc = __expf(m - p);
            l *= sc;
#pragma unroll
            for (int i = 0; i < 3; ++i) {
                acc[i].x *= sc; acc[i].y *= sc; acc[i].z *= sc; acc[i].w *= sc;
            }
            m = p;
        }
        float e = __expf(p - m);
        l += e;
        acc[0].x += e * x0.x; acc[0].y += e * x0.y; acc[0].z += e * x0.z; acc[0].w += e * x0.w;
        acc[1].x += e * x1.x; acc[1].y += e * x1.y; acc[1].z += e * x1.z; acc[1].w += e * x1.w;
        acc[2].x += e * x2.x; acc[2].y += e * x2.y; acc[2].z += e * x2.z; acc[2].w += e * x2.w;
    }
#pragma unroll
    for (int i = 0; i < 3; ++i)
        *(float4*)&acc_s[wv][4 * lane + 256 * i] = acc[i];
    if (lane == 0) { m_s[wv] = m; l_s[wv] = l; }
    __syncthreads();

    float M = fmaxf(fmaxf(m_s[0], m_s[1]), fmaxf(m_s[2], m_s[3]));
    float f0 = (l_s[0] > 0.f) ? __expf(m_s[0] - M) : 0.f;
    float f1 = (l_s[1] > 0.f) ? __expf(m_s[1] - M) : 0.f;
    float f2 = (l_s[2] > 0.f) ? __expf(m_s[2] - M) : 0.f;
    float f3 = (l_s[3] > 0.f) ? __expf(m_s[3] - M) : 0.f;
    float inv = 1.f / (l_s[0] * f0 + l_s[1] * f1 + l_s[2] * f2 + l_s[3] * f3);
    float* o = doc + ((size_t)s * B_ + b) * D_;
#pragma unroll
    for (int i = 0; i < 3; ++i) {
        int d = tid + 256 * i;
        float num = acc_s[0][d] * f0 + acc_s[1][d] * f1
                  + acc_s[2][d] * f2 + acc_s[3][d] * f3;
        o[d] = num * inv;
    }
}

// ---------------------------------------------------------------------------
// K2: gi = doc @ [Wf;Wb].T + bias via f16 dot2 (pack during staging).
// ---------------------------------------------------------------------------
__global__ __launch_bounds__(256) void gemm_enc(
    const float* __restrict__ A,
    const float* __restrict__ Wf, const float* __restrict__ Wb,
    const float* __restrict__ bf_, const float* __restrict__ bb_,
    float* __restrict__ C)
{
    __shared__ __align__(16) unsigned As[16][68];
    __shared__ __align__(16) unsigned Ws[16][68];
    int n0 = blockIdx.x * 64, m0 = blockIdx.y * 64;
    int tid = threadIdx.x;
    int tx = tid & 15, ty = tid >> 4;
    int lr = tid >> 2, lk4 = tid & 3;
    float acc[4][4] = {};

    for (int kk = 0; kk < 384; kk += 16) {
        {
            const float* ap = A + ((size_t)(m0 + lr)) * D_ + (kk + lk4 * 4) * 2;
            float4 x = *(const float4*)ap;
            float4 y = *(const float4*)(ap + 4);
            As[lk4 * 4 + 0][lr] = packh2(x.x, x.y);
            As[lk4 * 4 + 1][lr] = packh2(x.z, x.w);
            As[lk4 * 4 + 2][lr] = packh2(y.x, y.y);
            As[lk4 * 4 + 3][lr] = packh2(y.z, y.w);
            int n = n0 + lr;
            float4 u = make_float4(0.f, 0.f, 0.f, 0.f);
            float4 v = make_float4(0.f, 0.f, 0.f, 0.f);
            if (n < G3) {
                const float* wp = Wf + (size_t)n * D_ + (kk + lk4 * 4) * 2;
                u = *(const float4*)wp; v = *(const float4*)(wp + 4);
            } else if (n < 600) {
                const float* wp = Wb + (size_t)(n - G3) * D_ + (kk + lk4 * 4) * 2;
                u = *(const float4*)wp; v = *(const float4*)(wp + 4);
            }
            Ws[lk4 * 4 + 0][lr] = packh2(u.x, u.y);
            Ws[lk4 * 4 + 1][lr] = packh2(u.z, u.w);
            Ws[lk4 * 4 + 2][lr] = packh2(v.x, v.y);
            Ws[lk4 * 4 + 3][lr] = packh2(v.z, v.w);
        }
        __syncthreads();
#pragma unroll
        for (int ku = 0; ku < 16; ++ku) {
            uint4 av = *(const uint4*)&As[ku][ty * 4];
            uint4 wv = *(const uint4*)&Ws[ku][tx * 4];
            unsigned aa[4] = {av.x, av.y, av.z, av.w};
            unsigned ww[4] = {wv.x, wv.y, wv.z, wv.w};
#pragma unroll
            for (int i = 0; i < 4; ++i)
#pragma unroll
                for (int jj = 0; jj < 4; ++jj)
                    acc[i][jj] = __builtin_amdgcn_fdot2(u_as_h2(aa[i]), u_as_h2(ww[jj]),
                                                        acc[i][jj], false);
        }
        __syncthreads();
    }
#pragma unroll
    for (int jj = 0; jj < 4; ++jj) {
        int n = n0 + tx * 4 + jj;
        if (n >= 600) continue;
        float bias = (n < G3) ? bf_[n] : bb_[n - G3];
#pragma unroll
        for (int i = 0; i < 4; ++i) {
            int m = m0 + ty * 4 + i;
            C[(size_t)m * 600 + n] = acc[i][jj] + bias;
        }
    }
}

// ---------------------------------------------------------------------------
// K2b: gil = out1 @ W2.T + b2.  M=2048, N=300, K=200, f32 64x64 tiles.
// ---------------------------------------------------------------------------
__global__ __launch_bounds__(256) void gemm_gil(
    const float* __restrict__ A, const float* __restrict__ W,
    const float* __restrict__ bias, float* __restrict__ C)
{
    __shared__ __align__(16) float As[16][68];
    __shared__ __align__(16) float Ws[16][68];
    int n0 = blockIdx.x * 64, m0 = blockIdx.y * 64;
    int tid = threadIdx.x;
    int tx = tid & 15, ty = tid >> 4;
    int lr = tid >> 2, lk4 = tid & 3;
    float acc[4][4] = {};

    for (int kk = 0; kk < 208; kk += 16) {
        int k = kk + lk4 * 4;
        float4 av = make_float4(0.f, 0.f, 0.f, 0.f);
        if (k < 200) av = *(const float4*)(A + (size_t)(m0 + lr) * 200 + k);
        As[lk4 * 4 + 0][lr] = av.x; As[lk4 * 4 + 1][lr] = av.y;
        As[lk4 * 4 + 2][lr] = av.z; As[lk4 * 4 + 3][lr] = av.w;
        int n = n0 + lr;
        float4 wv = make_float4(0.f, 0.f, 0.f, 0.f);
        if (n < G3 && k < 200) wv = *(const float4*)(W + (size_t)n * 200 + k);
        Ws[lk4 * 4 + 0][lr] = wv.x; Ws[lk4 * 4 + 1][lr] = wv.y;
        Ws[lk4 * 4 + 2][lr] = wv.z; Ws[lk4 * 4 + 3][lr] = wv.w;
        __syncthreads();
#pragma unroll
        for (int ki = 0; ki < 16; ++ki) {
            float4 a4 = *(const float4*)&As[ki][ty * 4];
            float4 w4 = *(const float4*)&Ws[ki][tx * 4];
            float ai[4] = {a4.x, a4.y, a4.z, a4.w};
            float wj[4] = {w4.x, w4.y, w4.z, w4.w};
#pragma unroll
            for (int i = 0; i < 4; ++i)
#pragma unroll
                for (int jj = 0; jj < 4; ++jj) acc[i][jj] += ai[i] * wj[jj];
        }
        __syncthreads();
    }
#pragma unroll
    for (int jj = 0; jj < 4; ++jj) {
        int n = n0 + tx * 4 + jj;
        if (n >= G3) continue;
#pragma unroll
        for (int i = 0; i < 4; ++i) {
            int m = m0 + ty * 4 + i;
            C[(size_t)m * G3 + n] = acc[i][jj] + bias[n];
        }
    }
}

// ---------------------------------------------------------------------------
// Scan matvec core.
// ---------------------------------------------------------------------------
#define LOAD_WREGS(WPBASE)                                                  \
    uint4 wq[10];                                                           \
    if (mv) {                                                               \
        const uint4* wp_ = (const uint4*)((WPBASE) + (size_t)tid * 40);     \
        _Pragma("unroll")                                                   \
        for (int i = 0; i < 10; ++i) wq[i] = wp_[i];                        \
    }

#define WD(i) (((i) & 3) == 0 ? wq[(i) >> 2].x : ((i) & 3) == 1 ? wq[(i) >> 2].y \
             : ((i) & 3) == 2 ? wq[(i) >> 2].z : wq[(i) >> 2].w)

#define MATVEC_REG(PBUF)                                                    \
    {                                                                       \
        const unsigned* hh = (const unsigned*)(PBUF);                       \
        _Pragma("unroll")                                                   \
        for (int d = 0; d < 13; ++d) {                                      \
            half2_t hv = u_as_h2(hh[13 * q + d]);                           \
            ar = __builtin_amdgcn_fdot2(u_as_h2(WD(d)),      hv, ar, false); \
            az = __builtin_amdgcn_fdot2(u_as_h2(WD(13 + d)), hv, az, false); \
            an = __builtin_amdgcn_fdot2(u_as_h2(WD(26 + d)), hv, an, false); \
        }                                                                   \
        ar += __shfl_xor(ar, 1); ar += __shfl_xor(ar, 2);                   \
        az += __shfl_xor(az, 1); az += __shfl_xor(az, 2);                   \
        an += __shfl_xor(an, 1); an += __shfl_xor(an, 2);                   \
    }

// ---------------------------------------------------------------------------
// K3: encoder scans. 128 blocks = (b, dir), 448 thr, 1 barrier/step,
// unroll-2 g prefetch.
// ---------------------------------------------------------------------------
#define ENCT 448
#define ENC_SUB(GA0, GA1, GA2, NB0, NB1, NB2, SC, SN)                       \
    {                                                                       \
        if (mv) {                                                           \
            if (q == 0 && (SN) < S_) {                                      \
                int tn_ = bwd ? (S_ - 1 - (SN)) : (SN);                     \
                const float* gg_ = gi + ((size_t)tn_ * B_ + b) * 600 + goff; \
                NB0 = gg_[j]; NB1 = gg_[100 + j]; NB2 = gg_[200 + j];       \
            }                                                               \
            float ar = 0.f, az = 0.f, an = 0.f;                             \
            MATVEC_REG(hhalf[p])                                            \
            if (q == 0) {                                                   \
                int tc_ = bwd ? (S_ - 1 - (SC)) : (SC);                     \
                float r = sigmoidf_(GA0 + ar + bhr);                        \
                float z = sigmoidf_(GA1 + az + bhz);                        \
                float n = tanhf_(GA2 + r * (an + bhn));                     \
                float hn = (1.f - z) * n + z * hc;                          \
                hc = hn;                                                    \
                hhalf[p ^ 1][j] = (_Float16)hn;                             \
                out1[((size_t)tc_ * B_ + b) * 200 + ooff + j] = hn;         \
            }                                                               \
        }                                                                   \
        __syncthreads();                                                    \
        p ^= 1;                                                             \
    }

__global__ __launch_bounds__(ENCT, 1) void enc_scan(
    const float* __restrict__ gi, const unsigned* __restrict__ wpack,
    const float* __restrict__ bhh_f, const float* __restrict__ bhh_b,
    float* __restrict__ out1, float* __restrict__ hT)
{
    __shared__ __align__(8) _Float16 hhalf[2][104];

    int bid = blockIdx.x;
    int b = bid & 63;
    bool bwd = (bid >= 64);
    const float* bhh = bwd ? bhh_b : bhh_f;
    int tid = threadIdx.x;
    int j = tid >> 2, q = tid & 3;
    bool mv = tid < 400;
    const int goff = bwd ? G3 : 0;
    const int ooff = bwd ? H_ : 0;

    if (tid < 104) { hhalf[0][tid] = (_Float16)0.f; hhalf[1][tid] = (_Float16)0.f; }
    LOAD_WREGS(wpack + (bwd ? 16000 : 0))
    float bhr = 0.f, bhz = 0.f, bhn = 0.f, hc = 0.f;
    float pA0 = 0.f, pA1 = 0.f, pA2 = 0.f, pB0 = 0.f, pB1 = 0.f, pB2 = 0.f;
    if (mv && q == 0) {
        bhr = bhh[j]; bhz = bhh[100 + j]; bhn = bhh[200 + j];
        int t0 = bwd ? (S_ - 1) : 0;
        const float* gg = gi + ((size_t)t0 * B_ + b) * 600 + goff;
        pA0 = gg[j]; pA1 = gg[100 + j]; pA2 = gg[200 + j];
    }
    __syncthreads();

    int p = 0;
    for (int step = 0; step < S_; step += 2) {
        ENC_SUB(pA0, pA1, pA2, pB0, pB1, pB2, step, step + 1)
        ENC_SUB(pB0, pB1, pB2, pA0, pA1, pA2, step + 1, step + 2)
    }
    if (!bwd && mv && q == 0) hT[b * H_ + j] = hc;
}

// ---------------------------------------------------------------------------
// K5: decoder scan. 64 blocks, 448 thr, 1 barrier/step; argmax redundant
// per wave, softmax (exp/sum/log) only on wave 0.
// ---------------------------------------------------------------------------
#define DECT 448
#define DEC_LOGITS(TPREV)                                                   \
    {                                                                       \
        float acc_ = 0.f;                                                   \
        if (lane < 40) {                                                    \
            int c_ = lane >> 2, part_ = lane & 3;                           \
            const float* hr_ = hl_s + c_ * H_;                              \
            const float* hv_ = hf[p];                                       \
            int k0_ = 25 * part_;                                           \
            for (int k_ = k0_; k_ < k0_ + 25; ++k_) acc_ += hr_[k_] * hv_[k_]; \
            acc_ += __shfl_xor(acc_, 1);                                    \
            acc_ += __shfl_xor(acc_, 2);                                    \
        }                                                                   \
        float src_ = __shfl(acc_, (lane < NC_) ? 4 * lane : 0);             \
        float lv_ = (lane < NC_) ? src_ + hlb_r : -INFINITY;                \
        float mx_ = lv_; int am_ = lane & 15;                               \
        _Pragma("unroll")                                                   \
        for (int m_ = 8; m_; m_ >>= 1) {                                    \
            float ov_ = __shfl_xor(mx_, m_);                                \
            int oa_ = __shfl_xor(am_, m_);                                  \
            if (ov_ > mx_ || (ov_ == mx_ && oa_ < am_)) { mx_ = ov_; am_ = oa_; } \
        }                                                                   \
        if (w0) {                                                           \
            float e_ = (lane < NC_) ? __expf(lv_ - mx_) : 0.f;              \
            float se_ = e_;                                                 \
            _Pragma("unroll")                                               \
            for (int m_ = 8; m_; m_ >>= 1) se_ += __shfl_xor(se_, m_);      \
            if (lane < NC_) {                                               \
                float lse_ = mx_ + __logf(se_);                             \
                out[((size_t)(TPREV) * B_ + b) * NC_ + lane] = lv_ - lse_;  \
            }                                                               \
        }                                                                   \
        prev = __shfl(am_, 0);                                              \
    }

#define DEC_SUB(GA0, GA1, GA2, NB0, NB1, NB2, TC)                           \
    {                                                                       \
        float ar = 0.f, az = 0.f, an = 0.f;                                 \
        if (mv && (TC) < S_) {                                              \
            if (q == 0 && (TC) + 1 < S_) {                                  \
                const float* gg_ = gi_lin + ((size_t)((TC) + 1) * B_ + b) * G3; \
                NB0 = gg_[j]; NB1 = gg_[100 + j]; NB2 = gg_[200 + j];       \
            }                                                               \
            MATVEC_REG(hhalf[p])                                            \
        }                                                                   \
        if ((TC) >= 1) DEC_LOGITS((TC) - 1)                                 \
        if (mv && (TC) < S_ && q == 0) {                                    \
            const float* tcp_ = tc_s + prev * G3;                           \
            float r = sigmoidf_(GA0 + tcp_[j]       + ar + bhr);            \
            float z = sigmoidf_(GA1 + tcp_[100 + j] + az + bhz);            \
            float n = tanhf_(   GA2 + tcp_[200 + j] + r * (an + bhn));      \
            float hn = (1.f - z) * n + z * hc;                              \
            hc = hn;                                                        \
            hf[p ^ 1][j] = hn;                                              \
            hhalf[p ^ 1][j] = (_Float16)hn;                                 \
        }                                                                   \
        __syncthreads();                                                    \
        p ^= 1;                                                             \
    }

__global__ __launch_bounds__(DECT, 1) void dec_scan(
    const float* __restrict__ gi_lin, const unsigned* __restrict__ wpack,
    const float* __restrict__ bhh, const float* __restrict__ tcg,
    const float* __restrict__ h2lw, const float* __restrict__ h2lb,
    const float* __restrict__ hT, float* __restrict__ out)
{
    __shared__ float tc_s[NC_ * G3];
    __shared__ float hl_s[NC_ * H_];
    __shared__ __align__(8) _Float16 hhalf[2][104];
    __shared__ __align__(16) float hf[2][104];

    int bid = blockIdx.x;
    int b = bid & 63;
    int tid = threadIdx.x;
    int j = tid >> 2, q = tid & 3;
    bool mv = tid < 400;
    int lane = tid & 63;
    bool w0 = (tid < 64);

    for (int idx = tid; idx < NC_ * G3; idx += DECT) tc_s[idx] = tcg[idx];
    for (int idx = tid; idx < NC_ * H_; idx += DECT) hl_s[idx] = h2lw[idx];
    if (tid < 104) {
        float hv = (tid < H_) ? hT[b * H_ + tid] : 0.f;
        hf[0][tid] = hv;            hf[1][tid] = 0.f;
        hhalf[0][tid] = (_Float16)hv; hhalf[1][tid] = (_Float16)0.f;
    }
    LOAD_WREGS(wpack + 32000)
    float bhr = 0.f, bhz = 0.f, bhn = 0.f, hc = 0.f;
    float pA0 = 0.f, pA1 = 0.f, pA2 = 0.f, pB0 = 0.f, pB1 = 0.f, pB2 = 0.f;
    if (mv && q == 0) {
        bhr = bhh[j]; bhz = bhh[100 + j]; bhn = bhh[200 + j];
        hc = hT[b * H_ + j];
        const float* gg = gi_lin + ((size_t)0 * B_ + b) * G3;
        pA0 = gg[j]; pA1 = gg[100 + j]; pA2 = gg[200 + j];
    }
    float hlb_r = (lane < NC_) ? h2lb[lane] : 0.f;
    int prev = 0;
    __syncthreads();

    int p = 0;
    DEC_SUB(pA0, pA1, pA2, pB0, pB1, pB2, 0)
    for (int it = 0; it < 16; ++it) {
        int tA = 2 * it + 1, tB = 2 * it + 2;
        DEC_SUB(pB0, pB1, pB2, pA0, pA1, pA2, tA)
        DEC_SUB(pA0, pA1, pA2, pB0, pB1, pB2, tB)
    }
}

// ---------------------------------------------------------------------------
extern "C" void kernel_launch(void* const* d_in, const int* in_sizes, int n_in,
                              void* d_out, int out_size, void* d_ws, size_t ws_size,
                              hipStream_t stream)
{
    const float* hs   = (const float*)d_in[0];
    const int*   cb   = (const int*)  d_in[1];
    const float* fc5w = (const float*)d_in[2];
    const float* fc5b = (const float*)d_in[3];
    const float* ewif = (const float*)d_in[4];
    const float* ewhf = (const float*)d_in[5];
    const float* ebif = (const float*)d_in[6];
    const float* ebhf = (const float*)d_in[7];
    const float* ewib = (const float*)d_in[8];
    const float* ewhb = (const float*)d_in[9];
    const float* ebib = (const float*)d_in[10];
    const float* ebhb = (const float*)d_in[11];
    const float* emb  = (const float*)d_in[12];
    const float* l1w  = (const float*)d_in[13];
    const float* l1b  = (const float*)d_in[14];
    const float* dwih = (const float*)d_in[15];
    const float* dwhh = (const float*)d_in[16];
    const float* dbih = (const float*)d_in[17];
    const float* dbhh = (const float*)d_in[18];
    const float* h2lw = (const float*)d_in[19];
    const float* h2lb = (const float*)d_in[20];
    float* out = (float*)d_out;

    float* ws   = (float*)d_ws;
    float* doc  = ws;                  // [32*64, 768]   = 1572864
    float* gi   = doc  + 1572864;      // [2048, 600]    = 1228800
    float* out1 = gi   + 1228800;      // [2048, 200]    = 409600
    float* hT   = out1 + 409600;       // [64, 100]      = 6400
    float* W2   = hT   + 6400;         // [300, 200]     = 60000
    float* b2   = W2   + 60000;        // [300]
    float* tcg  = b2   + 320;          // [10, 300]      = 3000
    float* gil  = tcg  + 3072;         // [2048, 300]    = 614400
    unsigned* wpack = (unsigned*)(gil + 614400);  // 3 * 16000 dwords

    pool_prep_kernel<<<2351, 256, 0, stream>>>(
        hs, cb, fc5w, fc5b, doc,
        dwih, l1w, l1b, emb, dbih, W2, b2, tcg,
        ewhf, ewhb, dwhh, wpack);
    gemm_enc<<<dim3(10, 32), 256, 0, stream>>>(doc, ewif, ewib, ebif, ebib, gi);
    enc_scan<<<128, ENCT, 0, stream>>>(gi, wpack, ebhf, ebhb, out1, hT);
    gemm_gil<<<dim3(5, 32), 256, 0, stream>>>(out1, W2, b2, gil);
    dec_scan<<<64, DECT, 0, stream>>>(gil, wpack, dbhh, tcg,
                                      h2lw, h2lb, hT, out);
}

// Round 18
// 159.152 us; speedup vs baseline: 1.2874x; 1.0645x over previous
//
#include <hip/hip_runtime.h>
#include <hip/hip_bf16.h>
#include <math.h>

#define B_ 64
#define L_ 512
#define D_ 768
#define J_ 31
#define S_ 32
#define H_ 100
#define G3 300
#define NC_ 10
#define EMB_ 50

__device__ __forceinline__ float sigmoidf_(float x) { return 1.0f / (1.0f + __expf(-x)); }
__device__ __forceinline__ float tanhf_(float x) {
    float e = __expf(2.0f * x);
    return 1.0f - 2.0f / (e + 1.0f);
}
__device__ __forceinline__ float dot4f_(float4 a, float4 b) {
    return a.x * b.x + a.y * b.y + a.z * b.z + a.w * b.w;
}

typedef _Float16 half2_t __attribute__((ext_vector_type(2)));
typedef _Float16 f16x8 __attribute__((ext_vector_type(8)));
typedef float f32x4 __attribute__((ext_vector_type(4)));
__device__ __forceinline__ half2_t u_as_h2(unsigned u) { return __builtin_bit_cast(half2_t, u); }
__device__ __forceinline__ unsigned packh2(float a, float b) {
    half2_t p; p.x = (_Float16)a; p.y = (_Float16)b;
    return __builtin_bit_cast(unsigned, p);
}

// ---------------------------------------------------------------------------
// K1: fused pool + prep.
// Blocks 0..2047: pooling (s=bid>>6, b=bid&63), doc written as f16.
// Blocks 2048..2347: w2/b2/tcg precompute.  2348..2350: pack_whh.
// Blocks 2351..2502: pack [Wf;Wb] -> wh f16 [608][768], rows>=600 zero.
// ---------------------------------------------------------------------------
__global__ __launch_bounds__(256) void pool_prep_kernel(
    const float* __restrict__ hs, const int* __restrict__ cb,
    const float* __restrict__ fc5w, const float* __restrict__ fc5b,
    _Float16* __restrict__ doc_h,
    const float* __restrict__ dwih, const float* __restrict__ l1w,
    const float* __restrict__ l1b, const float* __restrict__ emb,
    const float* __restrict__ bih,
    float* __restrict__ W2, float* __restrict__ b2, float* __restrict__ tcg,
    const float* __restrict__ ewhf, const float* __restrict__ ewhb,
    const float* __restrict__ dwhh, unsigned* __restrict__ wpack,
    const float* __restrict__ ewif, const float* __restrict__ ewib,
    _Float16* __restrict__ wh)
{
    __shared__ __align__(16) float acc_s[4][D_];
    __shared__ float m_s[4], l_s[4];

    int bidx = blockIdx.x;
    int tid = threadIdx.x;

    if (bidx >= 2048) {
        if (bidx < 2348) {
            int n = bidx - 2048;
            __shared__ float dw_s[H_];
            int k = tid;
            if (k < H_) dw_s[k] = dwih[(size_t)n * 150 + 50 + k];
            __syncthreads();
            if (k < 200) {
                float acc = 0.f;
                for (int i = 0; i < H_; ++i) acc += dw_s[i] * l1w[(size_t)i * 200 + k];
                W2[(size_t)n * 200 + k] = acc;
            } else if (k == 200) {
                float acc = 0.f;
                for (int i = 0; i < H_; ++i) acc += dw_s[i] * l1b[i];
                b2[n] = acc;
            } else if (k < 211) {
                int c = k - 201;
                float acc = bih[n];
                const float* er = emb + c * EMB_;
                const float* wr = dwih + (size_t)n * 150;
                for (int e = 0; e < EMB_; ++e) acc += er[e] * wr[e];
                tcg[c * G3 + n] = acc;
            }
        } else if (bidx < 2351) {
            int m = bidx - 2348;
            const float* whh = (m == 0) ? ewhf : (m == 1) ? ewhb : dwhh;
            for (int t = tid; t < 400; t += 256) {
                int j = t >> 2, q = t & 3;
                unsigned* o = wpack + (size_t)m * 16000 + (size_t)t * 40;
#pragma unroll
                for (int d = 0; d < 13; ++d) {
                    int k = 2 * (13 * q + d);
                    float r0 = (k < H_) ? whh[j * H_ + k] : 0.f;
                    float r1 = (k + 1 < H_) ? whh[j * H_ + k + 1] : 0.f;
                    float z0 = (k < H_) ? whh[(100 + j) * H_ + k] : 0.f;
                    float z1 = (k + 1 < H_) ? whh[(100 + j) * H_ + k + 1] : 0.f;
                    float n0 = (k < H_) ? whh[(200 + j) * H_ + k] : 0.f;
                    float n1 = (k + 1 < H_) ? whh[(200 + j) * H_ + k + 1] : 0.f;
                    o[d]      = packh2(r0, r1);
                    o[13 + d] = packh2(z0, z1);
                    o[26 + d] = packh2(n0, n1);
                }
                o[39] = 0u;
            }
        } else {
            // pack enc input weights: wh[n][k], n<300: Wf, 300<=n<600: Wb, else 0
            int ri = bidx - 2351;            // 0..151 -> rows 4ri..4ri+3
            for (int idx = tid; idx < 3072; idx += 256) {
                int rr = idx >> 9;           // idx/768? no: 3072/4 = 768 per row
                // idx = rr*768 + k
                rr = idx / 768;
                int k = idx - rr * 768;
                int n = 4 * ri + rr;
                float v = 0.f;
                if (n < G3) v = ewif[(size_t)n * D_ + k];
                else if (n < 600) v = ewib[(size_t)(n - G3) * D_ + k];
                wh[(size_t)n * D_ + k] = (_Float16)v;
            }
        }
        return;
    }

    // ---- pooling for (s, b) ----
    int s = bidx >> 6, b = bidx & 63;
    int start = (s == 0) ? 0 : cb[b * J_ + s - 1];
    int end   = (s == J_) ? L_ : cb[b * J_ + s];
    int nt = end - start;
    int lane = tid & 63, wv = tid >> 6;

    if (nt <= 0) {
        for (int d = tid; d < D_; d += 256) doc_h[((size_t)s * B_ + b) * D_ + d] = (_Float16)0.f;
        return;
    }

    float4 fwv[3];
#pragma unroll
    for (int i = 0; i < 3; ++i)
        fwv[i] = *(const float4*)(fc5w + 4 * lane + 256 * i);
    float bias = fc5b[0];

    const float* base = hs + ((size_t)b * L_ + start) * D_;
    float m = -INFINITY, l = 0.f;
    float4 acc[3];
#pragma unroll
    for (int i = 0; i < 3; ++i) acc[i] = make_float4(0.f, 0.f, 0.f, 0.f);

    for (int t = wv; t < nt; t += 4) {
        const float* row = base + (size_t)t * D_;
        float4 x0 = *(const float4*)(row + 4 * lane);
        float4 x1 = *(const float4*)(row + 4 * lane + 256);
        float4 x2 = *(const float4*)(row + 4 * lane + 512);
        float p = dot4f_(x0, fwv[0]) + dot4f_(x1, fwv[1]) + dot4f_(x2, fwv[2]);
#pragma unroll
        for (int off = 32; off; off >>= 1) p += __shfl_xor(p, off);
        p += bias;
        if (p > m) {
            float sc = __expf(m - p);
            l *= sc;
#pragma unroll
            for (int i = 0; i < 3; ++i) {
                acc[i].x *= sc; acc[i].y *= sc; acc[i].z *= sc; acc[i].w *= sc;
            }
            m = p;
        }
        float e = __expf(p - m);
        l += e;
        acc[0].x += e * x0.x; acc[0].y += e * x0.y; acc[0].z += e * x0.z; acc[0].w += e * x0.w;
        acc[1].x += e * x1.x; acc[1].y += e * x1.y; acc[1].z += e * x1.z; acc[1].w += e * x1.w;
        acc[2].x += e * x2.x; acc[2].y += e * x2.y; acc[2].z += e * x2.z; acc[2].w += e * x2.w;
    }
#pragma unroll
    for (int i = 0; i < 3; ++i)
        *(float4*)&acc_s[wv][4 * lane + 256 * i] = acc[i];
    if (lane == 0) { m_s[wv] = m; l_s[wv] = l; }
    __syncthreads();

    float M = fmaxf(fmaxf(m_s[0], m_s[1]), fmaxf(m_s[2], m_s[3]));
    float f0 = (l_s[0] > 0.f) ? __expf(m_s[0] - M) : 0.f;
    float f1 = (l_s[1] > 0.f) ? __expf(m_s[1] - M) : 0.f;
    float f2 = (l_s[2] > 0.f) ? __expf(m_s[2] - M) : 0.f;
    float f3 = (l_s[3] > 0.f) ? __expf(m_s[3] - M) : 0.f;
    float inv = 1.f / (l_s[0] * f0 + l_s[1] * f1 + l_s[2] * f2 + l_s[3] * f3);
    _Float16* o = doc_h + ((size_t)s * B_ + b) * D_;
#pragma unroll
    for (int i = 0; i < 3; ++i) {
        int d = tid + 256 * i;
        float num = acc_s[0][d] * f0 + acc_s[1][d] * f1
                  + acc_s[2][d] * f2 + acc_s[3][d] * f3;
        o[d] = (_Float16)(num * inv);
    }
}

// ---------------------------------------------------------------------------
// K2: gi = doc_h @ wh.T + bias via MFMA 16x16x32 f16.
// Grid (38, 32): n-tile = bx (16 cols), waves cover m-tiles 4*by..4*by+3.
// Fragments loaded straight from L2 (doc_h 3MB + wh 0.9MB are L2-resident).
// A/B frag: lane l -> row/col (l&15), k-chunk (l>>4)*8 (contiguous 16B).
// C/D: col = lane&15, row = (lane>>4)*4 + reg.
// ---------------------------------------------------------------------------
__global__ __launch_bounds__(256) void gemm_enc_mfma(
    const _Float16* __restrict__ dh, const _Float16* __restrict__ wh,
    const float* __restrict__ bf_, const float* __restrict__ bb_,
    float* __restrict__ C)
{
    int w = threadIdx.x >> 6, l = threadIdx.x & 63;
    int m0 = (blockIdx.y * 4 + w) * 16;
    int n0 = blockIdx.x * 16;
    int rowA = m0 + (l & 15);
    int rowB = n0 + (l & 15);
    int kb = (l >> 4) * 8;

    const f16x8* ap = (const f16x8*)(dh + (size_t)rowA * D_ + kb);
    const f16x8* bp = (const f16x8*)(wh + (size_t)rowB * D_ + kb);
    f32x4 acc = {0.f, 0.f, 0.f, 0.f};
#pragma unroll
    for (int k = 0; k < 24; ++k) {
        f16x8 a = ap[k * 4];    // advance 32 f16 per iter
        f16x8 b = bp[k * 4];
        acc = __builtin_amdgcn_mfma_f32_16x16x32_f16(a, b, acc, 0, 0, 0);
    }
    int nc = n0 + (l & 15);
    if (nc < 600) {
        float bias = (nc < G3) ? bf_[nc] : bb_[nc - G3];
#pragma unroll
        for (int r = 0; r < 4; ++r) {
            int mr = m0 + (l >> 4) * 4 + r;
            C[(size_t)mr * 600 + nc] = acc[r] + bias;
        }
    }
}

// ---------------------------------------------------------------------------
// K2b: gil = out1 @ W2.T + b2.  M=2048, N=300, K=200, f32 64x64 tiles.
// ---------------------------------------------------------------------------
__global__ __launch_bounds__(256) void gemm_gil(
    const float* __restrict__ A, const float* __restrict__ W,
    const float* __restrict__ bias, float* __restrict__ C)
{
    __shared__ __align__(16) float As[16][68];
    __shared__ __align__(16) float Ws[16][68];
    int n0 = blockIdx.x * 64, m0 = blockIdx.y * 64;
    int tid = threadIdx.x;
    int tx = tid & 15, ty = tid >> 4;
    int lr = tid >> 2, lk4 = tid & 3;
    float acc[4][4] = {};

    for (int kk = 0; kk < 208; kk += 16) {
        int k = kk + lk4 * 4;
        float4 av = make_float4(0.f, 0.f, 0.f, 0.f);
        if (k < 200) av = *(const float4*)(A + (size_t)(m0 + lr) * 200 + k);
        As[lk4 * 4 + 0][lr] = av.x; As[lk4 * 4 + 1][lr] = av.y;
        As[lk4 * 4 + 2][lr] = av.z; As[lk4 * 4 + 3][lr] = av.w;
        int n = n0 + lr;
        float4 wv = make_float4(0.f, 0.f, 0.f, 0.f);
        if (n < G3 && k < 200) wv = *(const float4*)(W + (size_t)n * 200 + k);
        Ws[lk4 * 4 + 0][lr] = wv.x; Ws[lk4 * 4 + 1][lr] = wv.y;
        Ws[lk4 * 4 + 2][lr] = wv.z; Ws[lk4 * 4 + 3][lr] = wv.w;
        __syncthreads();
#pragma unroll
        for (int ki = 0; ki < 16; ++ki) {
            float4 a4 = *(const float4*)&As[ki][ty * 4];
            float4 w4 = *(const float4*)&Ws[ki][tx * 4];
            float ai[4] = {a4.x, a4.y, a4.z, a4.w};
            float wj[4] = {w4.x, w4.y, w4.z, w4.w};
#pragma unroll
            for (int i = 0; i < 4; ++i)
#pragma unroll
                for (int jj = 0; jj < 4; ++jj) acc[i][jj] += ai[i] * wj[jj];
        }
        __syncthreads();
    }
#pragma unroll
    for (int jj = 0; jj < 4; ++jj) {
        int n = n0 + tx * 4 + jj;
        if (n >= G3) continue;
#pragma unroll
        for (int i = 0; i < 4; ++i) {
            int m = m0 + ty * 4 + i;
            C[(size_t)m * G3 + n] = acc[i][jj] + bias[n];
        }
    }
}

// ---------------------------------------------------------------------------
// Scan matvec core.
// ---------------------------------------------------------------------------
#define LOAD_WREGS(WPBASE)                                                  \
    uint4 wq[10];                                                           \
    if (mv) {                                                               \
        const uint4* wp_ = (const uint4*)((WPBASE) + (size_t)tid * 40);     \
        _Pragma("unroll")                                                   \
        for (int i = 0; i < 10; ++i) wq[i] = wp_[i];                        \
    }

#define WD(i) (((i) & 3) == 0 ? wq[(i) >> 2].x : ((i) & 3) == 1 ? wq[(i) >> 2].y \
             : ((i) & 3) == 2 ? wq[(i) >> 2].z : wq[(i) >> 2].w)

#define MATVEC_REG(PBUF)                                                    \
    {                                                                       \
        const unsigned* hh = (const unsigned*)(PBUF);                       \
        _Pragma("unroll")                                                   \
        for (int d = 0; d < 13; ++d) {                                      \
            half2_t hv = u_as_h2(hh[13 * q + d]);                           \
            ar = __builtin_amdgcn_fdot2(u_as_h2(WD(d)),      hv, ar, false); \
            az = __builtin_amdgcn_fdot2(u_as_h2(WD(13 + d)), hv, az, false); \
            an = __builtin_amdgcn_fdot2(u_as_h2(WD(26 + d)), hv, an, false); \
        }                                                                   \
        ar += __shfl_xor(ar, 1); ar += __shfl_xor(ar, 2);                   \
        az += __shfl_xor(az, 1); az += __shfl_xor(az, 2);                   \
        an += __shfl_xor(an, 1); an += __shfl_xor(an, 2);                   \
    }

// ---------------------------------------------------------------------------
// K3: encoder scans. 128 blocks = (b, dir), 448 thr, 1 barrier/step,
// unroll-2 g prefetch.
// ---------------------------------------------------------------------------
#define ENCT 448
#define ENC_SUB(GA0, GA1, GA2, NB0, NB1, NB2, SC, SN)                       \
    {                                                                       \
        if (mv) {                                                           \
            if (q == 0 && (SN) < S_) {                                      \
                int tn_ = bwd ? (S_ - 1 - (SN)) : (SN);                     \
                const float* gg_ = gi + ((size_t)tn_ * B_ + b) * 600 + goff; \
                NB0 = gg_[j]; NB1 = gg_[100 + j]; NB2 = gg_[200 + j];       \
            }                                                               \
            float ar = 0.f, az = 0.f, an = 0.f;                             \
            MATVEC_REG(hhalf[p])                                            \
            if (q == 0) {                                                   \
                int tc_ = bwd ? (S_ - 1 - (SC)) : (SC);                     \
                float r = sigmoidf_(GA0 + ar + bhr);                        \
                float z = sigmoidf_(GA1 + az + bhz);                        \
                float n = tanhf_(GA2 + r * (an + bhn));                     \
                float hn = (1.f - z) * n + z * hc;                          \
                hc = hn;                                                    \
                hhalf[p ^ 1][j] = (_Float16)hn;                             \
                out1[((size_t)tc_ * B_ + b) * 200 + ooff + j] = hn;         \
            }                                                               \
        }                                                                   \
        __syncthreads();                                                    \
        p ^= 1;                                                             \
    }

__global__ __launch_bounds__(ENCT, 1) void enc_scan(
    const float* __restrict__ gi, const unsigned* __restrict__ wpack,
    const float* __restrict__ bhh_f, const float* __restrict__ bhh_b,
    float* __restrict__ out1, float* __restrict__ hT)
{
    __shared__ __align__(8) _Float16 hhalf[2][104];

    int bid = blockIdx.x;
    int b = bid & 63;
    bool bwd = (bid >= 64);
    const float* bhh = bwd ? bhh_b : bhh_f;
    int tid = threadIdx.x;
    int j = tid >> 2, q = tid & 3;
    bool mv = tid < 400;
    const int goff = bwd ? G3 : 0;
    const int ooff = bwd ? H_ : 0;

    if (tid < 104) { hhalf[0][tid] = (_Float16)0.f; hhalf[1][tid] = (_Float16)0.f; }
    LOAD_WREGS(wpack + (bwd ? 16000 : 0))
    float bhr = 0.f, bhz = 0.f, bhn = 0.f, hc = 0.f;
    float pA0 = 0.f, pA1 = 0.f, pA2 = 0.f, pB0 = 0.f, pB1 = 0.f, pB2 = 0.f;
    if (mv && q == 0) {
        bhr = bhh[j]; bhz = bhh[100 + j]; bhn = bhh[200 + j];
        int t0 = bwd ? (S_ - 1) : 0;
        const float* gg = gi + ((size_t)t0 * B_ + b) * 600 + goff;
        pA0 = gg[j]; pA1 = gg[100 + j]; pA2 = gg[200 + j];
    }
    __syncthreads();

    int p = 0;
    for (int step = 0; step < S_; step += 2) {
        ENC_SUB(pA0, pA1, pA2, pB0, pB1, pB2, step, step + 1)
        ENC_SUB(pB0, pB1, pB2, pA0, pA1, pA2, step + 1, step + 2)
    }
    if (!bwd && mv && q == 0) hT[b * H_ + j] = hc;
}

// ---------------------------------------------------------------------------
// K5: decoder scan. 64 blocks, 448 thr, 1 barrier/step; argmax redundant
// per wave, softmax (exp/sum/log) only on wave 0.
// ---------------------------------------------------------------------------
#define DECT 448
#define DEC_LOGITS(TPREV)                                                   \
    {                                                                       \
        float acc_ = 0.f;                                                   \
        if (lane < 40) {                                                    \
            int c_ = lane >> 2, part_ = lane & 3;                           \
            const float* hr_ = hl_s + c_ * H_;                              \
            const float* hv_ = hf[p];                                       \
            int k0_ = 25 * part_;                                           \
            for (int k_ = k0_; k_ < k0_ + 25; ++k_) acc_ += hr_[k_] * hv_[k_]; \
            acc_ += __shfl_xor(acc_, 1);                                    \
            acc_ += __shfl_xor(acc_, 2);                                    \
        }                                                                   \
        float src_ = __shfl(acc_, (lane < NC_) ? 4 * lane : 0);             \
        float lv_ = (lane < NC_) ? src_ + hlb_r : -INFINITY;                \
        float mx_ = lv_; int am_ = lane & 15;                               \
        _Pragma("unroll")                                                   \
        for (int m_ = 8; m_; m_ >>= 1) {                                    \
            float ov_ = __shfl_xor(mx_, m_);                                \
            int oa_ = __shfl_xor(am_, m_);                                  \
            if (ov_ > mx_ || (ov_ == mx_ && oa_ < am_)) { mx_ = ov_; am_ = oa_; } \
        }                                                                   \
        if (w0) {                                                           \
            float e_ = (lane < NC_) ? __expf(lv_ - mx_) : 0.f;              \
            float se_ = e_;                                                 \
            _Pragma("unroll")                                               \
            for (int m_ = 8; m_; m_ >>= 1) se_ += __shfl_xor(se_, m_);      \
            if (lane < NC_) {                                               \
                float lse_ = mx_ + __logf(se_);                             \
                out[((size_t)(TPREV) * B_ + b) * NC_ + lane] = lv_ - lse_;  \
            }                                                               \
        }                                                                   \
        prev = __shfl(am_, 0);                                              \
    }

#define DEC_SUB(GA0, GA1, GA2, NB0, NB1, NB2, TC)                           \
    {                                                                       \
        float ar = 0.f, az = 0.f, an = 0.f;                                 \
        if (mv && (TC) < S_) {                                              \
            if (q == 0 && (TC) + 1 < S_) {                                  \
                const float* gg_ = gi_lin + ((size_t)((TC) + 1) * B_ + b) * G3; \
                NB0 = gg_[j]; NB1 = gg_[100 + j]; NB2 = gg_[200 + j];       \
            }                                                               \
            MATVEC_REG(hhalf[p])                                            \
        }                                                                   \
        if ((TC) >= 1) DEC_LOGITS((TC) - 1)                                 \
        if (mv && (TC) < S_ && q == 0) {                                    \
            const float* tcp_ = tc_s + prev * G3;                           \
            float r = sigmoidf_(GA0 + tcp_[j]       + ar + bhr);            \
            float z = sigmoidf_(GA1 + tcp_[100 + j] + az + bhz);            \
            float n = tanhf_(   GA2 + tcp_[200 + j] + r * (an + bhn));      \
            float hn = (1.f - z) * n + z * hc;                              \
            hc = hn;                                                        \
            hf[p ^ 1][j] = hn;                                              \
            hhalf[p ^ 1][j] = (_Float16)hn;                                 \
        }                                                                   \
        __syncthreads();                                                    \
        p ^= 1;                                                             \
    }

__global__ __launch_bounds__(DECT, 1) void dec_scan(
    const float* __restrict__ gi_lin, const unsigned* __restrict__ wpack,
    const float* __restrict__ bhh, const float* __restrict__ tcg,
    const float* __restrict__ h2lw, const float* __restrict__ h2lb,
    const float* __restrict__ hT, float* __restrict__ out)
{
    __shared__ float tc_s[NC_ * G3];
    __shared__ float hl_s[NC_ * H_];
    __shared__ __align__(8) _Float16 hhalf[2][104];
    __shared__ __align__(16) float hf[2][104];

    int bid = blockIdx.x;
    int b = bid & 63;
    int tid = threadIdx.x;
    int j = tid >> 2, q = tid & 3;
    bool mv = tid < 400;
    int lane = tid & 63;
    bool w0 = (tid < 64);

    for (int idx = tid; idx < NC_ * G3; idx += DECT) tc_s[idx] = tcg[idx];
    for (int idx = tid; idx < NC_ * H_; idx += DECT) hl_s[idx] = h2lw[idx];
    if (tid < 104) {
        float hv = (tid < H_) ? hT[b * H_ + tid] : 0.f;
        hf[0][tid] = hv;            hf[1][tid] = 0.f;
        hhalf[0][tid] = (_Float16)hv; hhalf[1][tid] = (_Float16)0.f;
    }
    LOAD_WREGS(wpack + 32000)
    float bhr = 0.f, bhz = 0.f, bhn = 0.f, hc = 0.f;
    float pA0 = 0.f, pA1 = 0.f, pA2 = 0.f, pB0 = 0.f, pB1 = 0.f, pB2 = 0.f;
    if (mv && q == 0) {
        bhr = bhh[j]; bhz = bhh[100 + j]; bhn = bhh[200 + j];
        hc = hT[b * H_ + j];
        const float* gg = gi_lin + ((size_t)0 * B_ + b) * G3;
        pA0 = gg[j]; pA1 = gg[100 + j]; pA2 = gg[200 + j];
    }
    float hlb_r = (lane < NC_) ? h2lb[lane] : 0.f;
    int prev = 0;
    __syncthreads();

    int p = 0;
    DEC_SUB(pA0, pA1, pA2, pB0, pB1, pB2, 0)
    for (int it = 0; it < 16; ++it) {
        int tA = 2 * it + 1, tB = 2 * it + 2;
        DEC_SUB(pB0, pB1, pB2, pA0, pA1, pA2, tA)
        DEC_SUB(pA0, pA1, pA2, pB0, pB1, pB2, tB)
    }
}

// ---------------------------------------------------------------------------
extern "C" void kernel_launch(void* const* d_in, const int* in_sizes, int n_in,
                              void* d_out, int out_size, void* d_ws, size_t ws_size,
                              hipStream_t stream)
{
    const float* hs   = (const float*)d_in[0];
    const int*   cb   = (const int*)  d_in[1];
    const float* fc5w = (const float*)d_in[2];
    const float* fc5b = (const float*)d_in[3];
    const float* ewif = (const float*)d_in[4];
    const float* ewhf = (const float*)d_in[5];
    const float* ebif = (const float*)d_in[6];
    const float* ebhf = (const float*)d_in[7];
    const float* ewib = (const float*)d_in[8];
    const float* ewhb = (const float*)d_in[9];
    const float* ebib = (const float*)d_in[10];
    const float* ebhb = (const float*)d_in[11];
    const float* emb  = (const float*)d_in[12];
    const float* l1w  = (const float*)d_in[13];
    const float* l1b  = (const float*)d_in[14];
    const float* dwih = (const float*)d_in[15];
    const float* dwhh = (const float*)d_in[16];
    const float* dbih = (const float*)d_in[17];
    const float* dbhh = (const float*)d_in[18];
    const float* h2lw = (const float*)d_in[19];
    const float* h2lb = (const float*)d_in[20];
    float* out = (float*)d_out;

    float* ws   = (float*)d_ws;
    // doc slot (1572864 floats) reused: doc_h f16 [2048][768] = 786432 floats,
    // wh f16 [608][768] = 233472 floats at offset 800000.
    _Float16* doc_h = (_Float16*)ws;
    _Float16* wh    = (_Float16*)(ws + 800000);
    float* gi   = ws + 1572864;        // [2048, 600]    = 1228800
    float* out1 = gi   + 1228800;      // [2048, 200]    = 409600
    float* hT   = out1 + 409600;       // [64, 100]      = 6400
    float* W2   = hT   + 6400;         // [300, 200]     = 60000
    float* b2   = W2   + 60000;        // [300]
    float* tcg  = b2   + 320;          // [10, 300]      = 3000
    float* gil  = tcg  + 3072;         // [2048, 300]    = 614400
    unsigned* wpack = (unsigned*)(gil + 614400);  // 3 * 16000 dwords

    pool_prep_kernel<<<2503, 256, 0, stream>>>(
        hs, cb, fc5w, fc5b, doc_h,
        dwih, l1w, l1b, emb, dbih, W2, b2, tcg,
        ewhf, ewhb, dwhh, wpack,
        ewif, ewib, wh);
    gemm_enc_mfma<<<dim3(38, 32), 256, 0, stream>>>(doc_h, wh, ebif, ebib, gi);
    enc_scan<<<128, ENCT, 0, stream>>>(gi, wpack, ebhf, ebhb, out1, hT);
    gemm_gil<<<dim3(5, 32), 256, 0, stream>>>(out1, W2, b2, gil);
    dec_scan<<<64, DECT, 0, stream>>>(gil, wpack, dbhh, tcg,
                                      h2lw, h2lb, hT, out);
}

// Round 19
// 143.594 us; speedup vs baseline: 1.4269x; 1.1083x over previous
//
#include <hip/hip_runtime.h>
#include <hip/hip_bf16.h>
#include <math.h>

#define B_ 64
#define L_ 512
#define D_ 768
#define J_ 31
#define S_ 32
#define H_ 100
#define G3 300
#define NC_ 10
#define EMB_ 50
#define OP_ 224   // padded K for out1h/W2h (200 -> 224)

__device__ __forceinline__ float sigmoidf_(float x) { return 1.0f / (1.0f + __expf(-x)); }
__device__ __forceinline__ float tanhf_(float x) {
    float e = __expf(2.0f * x);
    return 1.0f - 2.0f / (e + 1.0f);
}
__device__ __forceinline__ float dot4f_(float4 a, float4 b) {
    return a.x * b.x + a.y * b.y + a.z * b.z + a.w * b.w;
}

typedef _Float16 half2_t __attribute__((ext_vector_type(2)));
typedef _Float16 f16x8 __attribute__((ext_vector_type(8)));
typedef float f32x4 __attribute__((ext_vector_type(4)));
__device__ __forceinline__ half2_t u_as_h2(unsigned u) { return __builtin_bit_cast(half2_t, u); }
__device__ __forceinline__ unsigned packh2(float a, float b) {
    half2_t p; p.x = (_Float16)a; p.y = (_Float16)b;
    return __builtin_bit_cast(unsigned, p);
}

// ---------------------------------------------------------------------------
// K1: fused pool + prep.
// 0..2047: pooling (doc as f16).  2048..2347: W2h/b2/tcg.  2348..2350:
// pack_whh.  2351..2502: pack [Wf;Wb] -> wh.  2503..2510: zero out1h pad
// cols.  2511: zero W2h rows 300..303.
// ---------------------------------------------------------------------------
__global__ __launch_bounds__(256) void pool_prep_kernel(
    const float* __restrict__ hs, const int* __restrict__ cb,
    const float* __restrict__ fc5w, const float* __restrict__ fc5b,
    _Float16* __restrict__ doc_h,
    const float* __restrict__ dwih, const float* __restrict__ l1w,
    const float* __restrict__ l1b, const float* __restrict__ emb,
    const float* __restrict__ bih,
    _Float16* __restrict__ W2h, float* __restrict__ b2, float* __restrict__ tcg,
    const float* __restrict__ ewhf, const float* __restrict__ ewhb,
    const float* __restrict__ dwhh, unsigned* __restrict__ wpack,
    const float* __restrict__ ewif, const float* __restrict__ ewib,
    _Float16* __restrict__ wh, _Float16* __restrict__ out1h)
{
    __shared__ __align__(16) float acc_s[4][D_];
    __shared__ float m_s[4], l_s[4];

    int bidx = blockIdx.x;
    int tid = threadIdx.x;

    if (bidx >= 2048) {
        if (bidx < 2348) {
            int n = bidx - 2048;
            __shared__ float dw_s[H_];
            int k = tid;
            if (k < H_) dw_s[k] = dwih[(size_t)n * 150 + 50 + k];
            __syncthreads();
            if (k < 200) {
                float acc = 0.f;
                for (int i = 0; i < H_; ++i) acc += dw_s[i] * l1w[(size_t)i * 200 + k];
                W2h[(size_t)n * OP_ + k] = (_Float16)acc;
            } else if (k == 200) {
                float acc = 0.f;
                for (int i = 0; i < H_; ++i) acc += dw_s[i] * l1b[i];
                b2[n] = acc;
            } else if (k < 211) {
                int c = k - 201;
                float acc = bih[n];
                const float* er = emb + c * EMB_;
                const float* wr = dwih + (size_t)n * 150;
                for (int e = 0; e < EMB_; ++e) acc += er[e] * wr[e];
                tcg[c * G3 + n] = acc;
            } else if (k < 235) {
                W2h[(size_t)n * OP_ + (k - 11)] = (_Float16)0.f;   // cols 200..223
            }
        } else if (bidx < 2351) {
            int m = bidx - 2348;
            const float* whh = (m == 0) ? ewhf : (m == 1) ? ewhb : dwhh;
            for (int t = tid; t < 400; t += 256) {
                int j = t >> 2, q = t & 3;
                unsigned* o = wpack + (size_t)m * 16000 + (size_t)t * 40;
#pragma unroll
                for (int d = 0; d < 13; ++d) {
                    int k = 2 * (13 * q + d);
                    float r0 = (k < H_) ? whh[j * H_ + k] : 0.f;
                    float r1 = (k + 1 < H_) ? whh[j * H_ + k + 1] : 0.f;
                    float z0 = (k < H_) ? whh[(100 + j) * H_ + k] : 0.f;
                    float z1 = (k + 1 < H_) ? whh[(100 + j) * H_ + k + 1] : 0.f;
                    float n0 = (k < H_) ? whh[(200 + j) * H_ + k] : 0.f;
                    float n1 = (k + 1 < H_) ? whh[(200 + j) * H_ + k + 1] : 0.f;
                    o[d]      = packh2(r0, r1);
                    o[13 + d] = packh2(z0, z1);
                    o[26 + d] = packh2(n0, n1);
                }
                o[39] = 0u;
            }
        } else if (bidx < 2503) {
            int ri = bidx - 2351;            // rows 4ri..4ri+3 of wh
            for (int idx = tid; idx < 3072; idx += 256) {
                int rr = idx / 768;
                int k = idx - rr * 768;
                int n = 4 * ri + rr;
                float v = 0.f;
                if (n < G3) v = ewif[(size_t)n * D_ + k];
                else if (n < 600) v = ewib[(size_t)(n - G3) * D_ + k];
                wh[(size_t)n * D_ + k] = (_Float16)v;
            }
        } else if (bidx < 2511) {
            // zero out1h pad cols [200,224) for 256 rows
            int r0 = (bidx - 2503) * 256 + tid;
            _Float16* row = out1h + (size_t)r0 * OP_;
            for (int c = 200; c < OP_; ++c) row[c] = (_Float16)0.f;
        } else {
            // zero W2h rows 300..303
            for (int idx = tid; idx < 4 * OP_; idx += 256) {
                int r = 300 + idx / OP_, c = idx % OP_;
                W2h[(size_t)r * OP_ + c] = (_Float16)0.f;
            }
        }
        return;
    }

    // ---- pooling for (s, b) ----
    int s = bidx >> 6, b = bidx & 63;
    int start = (s == 0) ? 0 : cb[b * J_ + s - 1];
    int end   = (s == J_) ? L_ : cb[b * J_ + s];
    int nt = end - start;
    int lane = tid & 63, wv = tid >> 6;

    if (nt <= 0) {
        for (int d = tid; d < D_; d += 256) doc_h[((size_t)s * B_ + b) * D_ + d] = (_Float16)0.f;
        return;
    }

    float4 fwv[3];
#pragma unroll
    for (int i = 0; i < 3; ++i)
        fwv[i] = *(const float4*)(fc5w + 4 * lane + 256 * i);
    float bias = fc5b[0];

    const float* base = hs + ((size_t)b * L_ + start) * D_;
    float m = -INFINITY, l = 0.f;
    float4 acc[3];
#pragma unroll
    for (int i = 0; i < 3; ++i) acc[i] = make_float4(0.f, 0.f, 0.f, 0.f);

    for (int t = wv; t < nt; t += 4) {
        const float* row = base + (size_t)t * D_;
        float4 x0 = *(const float4*)(row + 4 * lane);
        float4 x1 = *(const float4*)(row + 4 * lane + 256);
        float4 x2 = *(const float4*)(row + 4 * lane + 512);
        float p = dot4f_(x0, fwv[0]) + dot4f_(x1, fwv[1]) + dot4f_(x2, fwv[2]);
#pragma unroll
        for (int off = 32; off; off >>= 1) p += __shfl_xor(p, off);
        p += bias;
        if (p > m) {
            float sc = __expf(m - p);
            l *= sc;
#pragma unroll
            for (int i = 0; i < 3; ++i) {
                acc[i].x *= sc; acc[i].y *= sc; acc[i].z *= sc; acc[i].w *= sc;
            }
            m = p;
        }
        float e = __expf(p - m);
        l += e;
        acc[0].x += e * x0.x; acc[0].y += e * x0.y; acc[0].z += e * x0.z; acc[0].w += e * x0.w;
        acc[1].x += e * x1.x; acc[1].y += e * x1.y; acc[1].z += e * x1.z; acc[1].w += e * x1.w;
        acc[2].x += e * x2.x; acc[2].y += e * x2.y; acc[2].z += e * x2.z; acc[2].w += e * x2.w;
    }
#pragma unroll
    for (int i = 0; i < 3; ++i)
        *(float4*)&acc_s[wv][4 * lane + 256 * i] = acc[i];
    if (lane == 0) { m_s[wv] = m; l_s[wv] = l; }
    __syncthreads();

    float M = fmaxf(fmaxf(m_s[0], m_s[1]), fmaxf(m_s[2], m_s[3]));
    float f0 = (l_s[0] > 0.f) ? __expf(m_s[0] - M) : 0.f;
    float f1 = (l_s[1] > 0.f) ? __expf(m_s[1] - M) : 0.f;
    float f2 = (l_s[2] > 0.f) ? __expf(m_s[2] - M) : 0.f;
    float f3 = (l_s[3] > 0.f) ? __expf(m_s[3] - M) : 0.f;
    float inv = 1.f / (l_s[0] * f0 + l_s[1] * f1 + l_s[2] * f2 + l_s[3] * f3);
    _Float16* o = doc_h + ((size_t)s * B_ + b) * D_;
#pragma unroll
    for (int i = 0; i < 3; ++i) {
        int d = tid + 256 * i;
        float num = acc_s[0][d] * f0 + acc_s[1][d] * f1
                  + acc_s[2][d] * f2 + acc_s[3][d] * f3;
        o[d] = (_Float16)(num * inv);
    }
}

// ---------------------------------------------------------------------------
// K2: gi = doc_h @ wh.T + bias via MFMA 16x16x32 f16.
// ---------------------------------------------------------------------------
__global__ __launch_bounds__(256) void gemm_enc_mfma(
    const _Float16* __restrict__ dh, const _Float16* __restrict__ wh,
    const float* __restrict__ bf_, const float* __restrict__ bb_,
    float* __restrict__ C)
{
    int w = threadIdx.x >> 6, l = threadIdx.x & 63;
    int m0 = (blockIdx.y * 4 + w) * 16;
    int n0 = blockIdx.x * 16;
    int rowA = m0 + (l & 15);
    int rowB = n0 + (l & 15);
    int kb = (l >> 4) * 8;

    const f16x8* ap = (const f16x8*)(dh + (size_t)rowA * D_ + kb);
    const f16x8* bp = (const f16x8*)(wh + (size_t)rowB * D_ + kb);
    f32x4 acc = {0.f, 0.f, 0.f, 0.f};
#pragma unroll
    for (int k = 0; k < 24; ++k) {
        f16x8 a = ap[k * 4];
        f16x8 b = bp[k * 4];
        acc = __builtin_amdgcn_mfma_f32_16x16x32_f16(a, b, acc, 0, 0, 0);
    }
    int nc = n0 + (l & 15);
    if (nc < 600) {
        float bias = (nc < G3) ? bf_[nc] : bb_[nc - G3];
#pragma unroll
        for (int r = 0; r < 4; ++r) {
            int mr = m0 + (l >> 4) * 4 + r;
            C[(size_t)mr * 600 + nc] = acc[r] + bias;
        }
    }
}

// ---------------------------------------------------------------------------
// K2b: gil = out1h @ W2h.T + b2 via MFMA.  M=2048, N=304, K=224 (padded).
// ---------------------------------------------------------------------------
__global__ __launch_bounds__(256) void gemm_gil_mfma(
    const _Float16* __restrict__ oh, const _Float16* __restrict__ W2h,
    const float* __restrict__ b2, float* __restrict__ C)
{
    int w = threadIdx.x >> 6, l = threadIdx.x & 63;
    int m0 = (blockIdx.y * 4 + w) * 16;
    int n0 = blockIdx.x * 16;
    const f16x8* ap = (const f16x8*)(oh + (size_t)(m0 + (l & 15)) * OP_ + (l >> 4) * 8);
    const f16x8* bp = (const f16x8*)(W2h + (size_t)(n0 + (l & 15)) * OP_ + (l >> 4) * 8);
    f32x4 acc = {0.f, 0.f, 0.f, 0.f};
#pragma unroll
    for (int k = 0; k < 7; ++k) {
        f16x8 a = ap[k * 4];
        f16x8 b = bp[k * 4];
        acc = __builtin_amdgcn_mfma_f32_16x16x32_f16(a, b, acc, 0, 0, 0);
    }
    int nc = n0 + (l & 15);
    if (nc < G3) {
        float bias = b2[nc];
#pragma unroll
        for (int r = 0; r < 4; ++r) {
            int mr = m0 + (l >> 4) * 4 + r;
            C[(size_t)mr * G3 + nc] = acc[r] + bias;
        }
    }
}

// ---------------------------------------------------------------------------
// Scan matvec core.
// ---------------------------------------------------------------------------
#define LOAD_WREGS(WPBASE)                                                  \
    uint4 wq[10];                                                           \
    if (mv) {                                                               \
        const uint4* wp_ = (const uint4*)((WPBASE) + (size_t)tid * 40);     \
        _Pragma("unroll")                                                   \
        for (int i = 0; i < 10; ++i) wq[i] = wp_[i];                        \
    }

#define WD(i) (((i) & 3) == 0 ? wq[(i) >> 2].x : ((i) & 3) == 1 ? wq[(i) >> 2].y \
             : ((i) & 3) == 2 ? wq[(i) >> 2].z : wq[(i) >> 2].w)

#define MATVEC_REG(PBUF)                                                    \
    {                                                                       \
        const unsigned* hh = (const unsigned*)(PBUF);                       \
        _Pragma("unroll")                                                   \
        for (int d = 0; d < 13; ++d) {                                      \
            half2_t hv = u_as_h2(hh[13 * q + d]);                           \
            ar = __builtin_amdgcn_fdot2(u_as_h2(WD(d)),      hv, ar, false); \
            az = __builtin_amdgcn_fdot2(u_as_h2(WD(13 + d)), hv, az, false); \
            an = __builtin_amdgcn_fdot2(u_as_h2(WD(26 + d)), hv, an, false); \
        }                                                                   \
        ar += __shfl_xor(ar, 1); ar += __shfl_xor(ar, 2);                   \
        az += __shfl_xor(az, 1); az += __shfl_xor(az, 2);                   \
        an += __shfl_xor(an, 1); an += __shfl_xor(an, 2);                   \
    }

// ---------------------------------------------------------------------------
// K3: encoder scans. 128 blocks = (b, dir), 448 thr, 1 barrier/step,
// unroll-2 g prefetch.  out1 written as f16 (stride OP_=224).
// ---------------------------------------------------------------------------
#define ENCT 448
#define ENC_SUB(GA0, GA1, GA2, NB0, NB1, NB2, SC, SN)                       \
    {                                                                       \
        if (mv) {                                                           \
            if (q == 0 && (SN) < S_) {                                      \
                int tn_ = bwd ? (S_ - 1 - (SN)) : (SN);                     \
                const float* gg_ = gi + ((size_t)tn_ * B_ + b) * 600 + goff; \
                NB0 = gg_[j]; NB1 = gg_[100 + j]; NB2 = gg_[200 + j];       \
            }                                                               \
            float ar = 0.f, az = 0.f, an = 0.f;                             \
            MATVEC_REG(hhalf[p])                                            \
            if (q == 0) {                                                   \
                int tc_ = bwd ? (S_ - 1 - (SC)) : (SC);                     \
                float r = sigmoidf_(GA0 + ar + bhr);                        \
                float z = sigmoidf_(GA1 + az + bhz);                        \
                float n = tanhf_(GA2 + r * (an + bhn));                     \
                float hn = (1.f - z) * n + z * hc;                          \
                hc = hn;                                                    \
                hhalf[p ^ 1][j] = (_Float16)hn;                             \
                out1h[((size_t)tc_ * B_ + b) * OP_ + ooff + j] = (_Float16)hn; \
            }                                                               \
        }                                                                   \
        __syncthreads();                                                    \
        p ^= 1;                                                             \
    }

__global__ __launch_bounds__(ENCT, 1) void enc_scan(
    const float* __restrict__ gi, const unsigned* __restrict__ wpack,
    const float* __restrict__ bhh_f, const float* __restrict__ bhh_b,
    _Float16* __restrict__ out1h, float* __restrict__ hT)
{
    __shared__ __align__(8) _Float16 hhalf[2][104];

    int bid = blockIdx.x;
    int b = bid & 63;
    bool bwd = (bid >= 64);
    const float* bhh = bwd ? bhh_b : bhh_f;
    int tid = threadIdx.x;
    int j = tid >> 2, q = tid & 3;
    bool mv = tid < 400;
    const int goff = bwd ? G3 : 0;
    const int ooff = bwd ? H_ : 0;

    if (tid < 104) { hhalf[0][tid] = (_Float16)0.f; hhalf[1][tid] = (_Float16)0.f; }
    LOAD_WREGS(wpack + (bwd ? 16000 : 0))
    float bhr = 0.f, bhz = 0.f, bhn = 0.f, hc = 0.f;
    float pA0 = 0.f, pA1 = 0.f, pA2 = 0.f, pB0 = 0.f, pB1 = 0.f, pB2 = 0.f;
    if (mv && q == 0) {
        bhr = bhh[j]; bhz = bhh[100 + j]; bhn = bhh[200 + j];
        int t0 = bwd ? (S_ - 1) : 0;
        const float* gg = gi + ((size_t)t0 * B_ + b) * 600 + goff;
        pA0 = gg[j]; pA1 = gg[100 + j]; pA2 = gg[200 + j];
    }
    __syncthreads();

    int p = 0;
    for (int step = 0; step < S_; step += 2) {
        ENC_SUB(pA0, pA1, pA2, pB0, pB1, pB2, step, step + 1)
        ENC_SUB(pB0, pB1, pB2, pA0, pA1, pA2, step + 1, step + 2)
    }
    if (!bwd && mv && q == 0) hT[b * H_ + j] = hc;
}

// ---------------------------------------------------------------------------
// K5: decoder scan. 64 blocks, 448 thr, 1 barrier/step; argmax redundant
// per wave, softmax (exp/sum/log) only on wave 0.
// ---------------------------------------------------------------------------
#define DECT 448
#define DEC_LOGITS(TPREV)                                                   \
    {                                                                       \
        float acc_ = 0.f;                                                   \
        if (lane < 40) {                                                    \
            int c_ = lane >> 2, part_ = lane & 3;                           \
            const float* hr_ = hl_s + c_ * H_;                              \
            const float* hv_ = hf[p];                                       \
            int k0_ = 25 * part_;                                           \
            for (int k_ = k0_; k_ < k0_ + 25; ++k_) acc_ += hr_[k_] * hv_[k_]; \
            acc_ += __shfl_xor(acc_, 1);                                    \
            acc_ += __shfl_xor(acc_, 2);                                    \
        }                                                                   \
        float src_ = __shfl(acc_, (lane < NC_) ? 4 * lane : 0);             \
        float lv_ = (lane < NC_) ? src_ + hlb_r : -INFINITY;                \
        float mx_ = lv_; int am_ = lane & 15;                               \
        _Pragma("unroll")                                                   \
        for (int m_ = 8; m_; m_ >>= 1) {                                    \
            float ov_ = __shfl_xor(mx_, m_);                                \
            int oa_ = __shfl_xor(am_, m_);                                  \
            if (ov_ > mx_ || (ov_ == mx_ && oa_ < am_)) { mx_ = ov_; am_ = oa_; } \
        }                                                                   \
        if (w0) {                                                           \
            float e_ = (lane < NC_) ? __expf(lv_ - mx_) : 0.f;              \
            float se_ = e_;                                                 \
            _Pragma("unroll")                                               \
            for (int m_ = 8; m_; m_ >>= 1) se_ += __shfl_xor(se_, m_);      \
            if (lane < NC_) {                                               \
                float lse_ = mx_ + __logf(se_);                             \
                out[((size_t)(TPREV) * B_ + b) * NC_ + lane] = lv_ - lse_;  \
            }                                                               \
        }                                                                   \
        prev = __shfl(am_, 0);                                              \
    }

#define DEC_SUB(GA0, GA1, GA2, NB0, NB1, NB2, TC)                           \
    {                                                                       \
        float ar = 0.f, az = 0.f, an = 0.f;                                 \
        if (mv && (TC) < S_) {                                              \
            if (q == 0 && (TC) + 1 < S_) {                                  \
                const float* gg_ = gi_lin + ((size_t)((TC) + 1) * B_ + b) * G3; \
                NB0 = gg_[j]; NB1 = gg_[100 + j]; NB2 = gg_[200 + j];       \
            }                                                               \
            MATVEC_REG(hhalf[p])                                            \
        }                                                                   \
        if ((TC) >= 1) DEC_LOGITS((TC) - 1)                                 \
        if (mv && (TC) < S_ && q == 0) {                                    \
            const float* tcp_ = tc_s + prev * G3;                           \
            float r = sigmoidf_(GA0 + tcp_[j]       + ar + bhr);            \
            float z = sigmoidf_(GA1 + tcp_[100 + j] + az + bhz);            \
            float n = tanhf_(   GA2 + tcp_[200 + j] + r * (an + bhn));      \
            float hn = (1.f - z) * n + z * hc;                              \
            hc = hn;                                                        \
            hf[p ^ 1][j] = hn;                                              \
            hhalf[p ^ 1][j] = (_Float16)hn;                                 \
        }                                                                   \
        __syncthreads();                                                    \
        p ^= 1;                                                             \
    }

__global__ __launch_bounds__(DECT, 1) void dec_scan(
    const float* __restrict__ gi_lin, const unsigned* __restrict__ wpack,
    const float* __restrict__ bhh, const float* __restrict__ tcg,
    const float* __restrict__ h2lw, const float* __restrict__ h2lb,
    const float* __restrict__ hT, float* __restrict__ out)
{
    __shared__ float tc_s[NC_ * G3];
    __shared__ float hl_s[NC_ * H_];
    __shared__ __align__(8) _Float16 hhalf[2][104];
    __shared__ __align__(16) float hf[2][104];

    int bid = blockIdx.x;
    int b = bid & 63;
    int tid = threadIdx.x;
    int j = tid >> 2, q = tid & 3;
    bool mv = tid < 400;
    int lane = tid & 63;
    bool w0 = (tid < 64);

    for (int idx = tid; idx < NC_ * G3; idx += DECT) tc_s[idx] = tcg[idx];
    for (int idx = tid; idx < NC_ * H_; idx += DECT) hl_s[idx] = h2lw[idx];
    if (tid < 104) {
        float hv = (tid < H_) ? hT[b * H_ + tid] : 0.f;
        hf[0][tid] = hv;            hf[1][tid] = 0.f;
        hhalf[0][tid] = (_Float16)hv; hhalf[1][tid] = (_Float16)0.f;
    }
    LOAD_WREGS(wpack + 32000)
    float bhr = 0.f, bhz = 0.f, bhn = 0.f, hc = 0.f;
    float pA0 = 0.f, pA1 = 0.f, pA2 = 0.f, pB0 = 0.f, pB1 = 0.f, pB2 = 0.f;
    if (mv && q == 0) {
        bhr = bhh[j]; bhz = bhh[100 + j]; bhn = bhh[200 + j];
        hc = hT[b * H_ + j];
        const float* gg = gi_lin + ((size_t)0 * B_ + b) * G3;
        pA0 = gg[j]; pA1 = gg[100 + j]; pA2 = gg[200 + j];
    }
    float hlb_r = (lane < NC_) ? h2lb[lane] : 0.f;
    int prev = 0;
    __syncthreads();

    int p = 0;
    DEC_SUB(pA0, pA1, pA2, pB0, pB1, pB2, 0)
    for (int it = 0; it < 16; ++it) {
        int tA = 2 * it + 1, tB = 2 * it + 2;
        DEC_SUB(pB0, pB1, pB2, pA0, pA1, pA2, tA)
        DEC_SUB(pA0, pA1, pA2, pB0, pB1, pB2, tB)
    }
}

// ---------------------------------------------------------------------------
extern "C" void kernel_launch(void* const* d_in, const int* in_sizes, int n_in,
                              void* d_out, int out_size, void* d_ws, size_t ws_size,
                              hipStream_t stream)
{
    const float* hs   = (const float*)d_in[0];
    const int*   cb   = (const int*)  d_in[1];
    const float* fc5w = (const float*)d_in[2];
    const float* fc5b = (const float*)d_in[3];
    const float* ewif = (const float*)d_in[4];
    const float* ewhf = (const float*)d_in[5];
    const float* ebif = (const float*)d_in[6];
    const float* ebhf = (const float*)d_in[7];
    const float* ewib = (const float*)d_in[8];
    const float* ewhb = (const float*)d_in[9];
    const float* ebib = (const float*)d_in[10];
    const float* ebhb = (const float*)d_in[11];
    const float* emb  = (const float*)d_in[12];
    const float* l1w  = (const float*)d_in[13];
    const float* l1b  = (const float*)d_in[14];
    const float* dwih = (const float*)d_in[15];
    const float* dwhh = (const float*)d_in[16];
    const float* dbih = (const float*)d_in[17];
    const float* dbhh = (const float*)d_in[18];
    const float* h2lw = (const float*)d_in[19];
    const float* h2lb = (const float*)d_in[20];
    float* out = (float*)d_out;

    float* ws   = (float*)d_ws;
    _Float16* doc_h = (_Float16*)ws;                  // [2048][768] f16
    _Float16* wh    = (_Float16*)(ws + 800000);       // [608][768] f16
    float* gi    = ws + 1572864;                      // [2048][600] f32
    _Float16* out1h = (_Float16*)(gi + 1228800);      // [2048][224] f16 = 229376 fl
    float* hT    = gi + 1228800 + 230000;             // [64][100]
    float* b2    = hT + 6400;                         // [300]
    float* tcg   = b2 + 320;                          // [10][300]
    float* gil   = tcg + 3072;                        // [2048][300]
    unsigned* wpack = (unsigned*)(gil + 614400);      // 48000 dwords
    _Float16* W2h = (_Float16*)(wpack + 48000);       // [304][224] f16

    pool_prep_kernel<<<2512, 256, 0, stream>>>(
        hs, cb, fc5w, fc5b, doc_h,
        dwih, l1w, l1b, emb, dbih, W2h, b2, tcg,
        ewhf, ewhb, dwhh, wpack,
        ewif, ewib, wh, out1h);
    gemm_enc_mfma<<<dim3(38, 32), 256, 0, stream>>>(doc_h, wh, ebif, ebib, gi);
    enc_scan<<<128, ENCT, 0, stream>>>(gi, wpack, ebhf, ebhb, out1h, hT);
    gemm_gil_mfma<<<dim3(19, 32), 256, 0, stream>>>(out1h, W2h, b2, gil);
    dec_scan<<<64, DECT, 0, stream>>>(gil, wpack, dbhh, tcg,
                                      h2lw, h2lb, hT, out);
}